// Round 1
// baseline (4545.571 us; speedup 1.0000x reference)
//
#include <hip/hip_runtime.h>

#define HID 128

// ---------------- degree ----------------
__global__ __launch_bounds__(256) void gc_deg_count(const int* __restrict__ col,
                                                    float* __restrict__ deg, int E) {
    int e = blockIdx.x * 256 + threadIdx.x;
    if (e < E) unsafeAtomicAdd(&deg[col[e]], 1.0f);
}

__global__ __launch_bounds__(256) void gc_deg_finish(float* __restrict__ deg, int n) {
    int i = blockIdx.x * 256 + threadIdx.x;
    if (i < n) deg[i] = 1.0f / sqrtf(deg[i] + 1.0f);  // +1 for self-loop; deg>=1 always
}

// ---------------- edge scatter: dst[col] += src[row] * (dinv[row]*dinv[col] or 1) ----
// half-wave per edge: 32 lanes x float4 = 128 floats
__global__ __launch_bounds__(256) void gc_edge_scatter(const int* __restrict__ row,
                                                       const int* __restrict__ col,
                                                       const float* __restrict__ src,
                                                       const float* __restrict__ dinv,
                                                       float* __restrict__ dst, int E) {
    long long gid = (long long)blockIdx.x * 256 + threadIdx.x;
    if (gid >= (long long)E * 32) return;
    int e = (int)(gid >> 5);
    int c = (int)(gid & 31);
    int r = row[e], cl = col[e];
    float s = 1.0f;
    if (dinv) s = dinv[r] * dinv[cl];
    float4 v = reinterpret_cast<const float4*>(src)[(long long)r * 32 + c];
    float* base = dst + (long long)cl * HID + c * 4;
    unsafeAtomicAdd(base + 0, v.x * s);
    unsafeAtomicAdd(base + 1, v.y * s);
    unsafeAtomicAdd(base + 2, v.z * s);
    unsafeAtomicAdd(base + 3, v.w * s);
}

// ---------------- self-loop + bias (+relu): dst += hp*dinv^2 + b ----------------
__global__ __launch_bounds__(256) void gc_self_bias(float* __restrict__ dst,
                                                    const float* __restrict__ hp,
                                                    const float* __restrict__ dinv,
                                                    const float* __restrict__ b,
                                                    int n, int do_relu) {
    int gid = blockIdx.x * 256 + threadIdx.x;  // over n*32
    if (gid >= n * 32) return;
    int node = gid >> 5, c = gid & 31;
    float di = dinv[node];
    float di2 = di * di;
    float4 a = reinterpret_cast<float4*>(dst)[gid];
    float4 h = reinterpret_cast<const float4*>(hp)[gid];
    float4 r;
    r.x = a.x + h.x * di2 + b[c * 4 + 0];
    r.y = a.y + h.y * di2 + b[c * 4 + 1];
    r.z = a.z + h.z * di2 + b[c * 4 + 2];
    r.w = a.w + h.w * di2 + b[c * 4 + 3];
    if (do_relu) {
        r.x = fmaxf(r.x, 0.f); r.y = fmaxf(r.y, 0.f);
        r.z = fmaxf(r.z, 0.f); r.w = fmaxf(r.w, 0.f);
    }
    reinterpret_cast<float4*>(dst)[gid] = r;
}

// ---------------- GEMM: out[n][m] = (A1@W1.T)[n][m] (+ A2@W2.T) (+bias) (relu) ------
// K = M = 128 fixed. 32 rows/block, 256 threads, 4x4 register tile per thread.
__global__ __launch_bounds__(256) void gc_gemm128(const float* __restrict__ A1,
                                                  const float* __restrict__ W1,
                                                  const float* __restrict__ A2,
                                                  const float* __restrict__ W2,
                                                  const float* __restrict__ bias,
                                                  float* __restrict__ out,
                                                  int nrows, int do_relu) {
    __shared__ __attribute__((aligned(16))) float Wt[2][32][132];  // [mat][k][m]
    __shared__ __attribute__((aligned(16))) float As[2][32][36];   // [mat][r][k]
    const int tx = threadIdx.x;
    const int nbase = blockIdx.x * 32;
    const int n0 = (tx >> 5) * 4;   // 0,4,...,28
    const int m0 = (tx & 31) * 4;   // 0,4,...,124
    const bool dual = (A2 != nullptr);

    float acc[4][4];
#pragma unroll
    for (int i = 0; i < 4; ++i)
#pragma unroll
        for (int j = 0; j < 4; ++j) acc[i][j] = 0.f;

    for (int kt = 0; kt < 128; kt += 32) {
#pragma unroll
        for (int i = 0; i < 16; ++i) {
            int idx = i * 256 + tx;
            int m = idx >> 5, k = idx & 31;
            Wt[0][k][m] = W1[m * 128 + kt + k];
        }
        if (dual) {
#pragma unroll
            for (int i = 0; i < 16; ++i) {
                int idx = i * 256 + tx;
                int m = idx >> 5, k = idx & 31;
                Wt[1][k][m] = W2[m * 128 + kt + k];
            }
        }
#pragma unroll
        for (int i = 0; i < 4; ++i) {
            int idx = i * 256 + tx;
            int r = idx >> 5, k = idx & 31;
            int rw = nbase + r;
            As[0][r][k] = (rw < nrows) ? A1[(long long)rw * 128 + kt + k] : 0.f;
        }
        if (dual) {
#pragma unroll
            for (int i = 0; i < 4; ++i) {
                int idx = i * 256 + tx;
                int r = idx >> 5, k = idx & 31;
                int rw = nbase + r;
                As[1][r][k] = (rw < nrows) ? A2[(long long)rw * 128 + kt + k] : 0.f;
            }
        }
        __syncthreads();

        for (int mat = 0; mat < (dual ? 2 : 1); ++mat) {
#pragma unroll
            for (int k = 0; k < 32; k += 4) {
                float a_s[4][4], w_s[4][4];
#pragma unroll
                for (int i = 0; i < 4; ++i)
                    *reinterpret_cast<float4*>(a_s[i]) =
                        *reinterpret_cast<const float4*>(&As[mat][n0 + i][k]);
#pragma unroll
                for (int kk = 0; kk < 4; ++kk)
                    *reinterpret_cast<float4*>(w_s[kk]) =
                        *reinterpret_cast<const float4*>(&Wt[mat][k + kk][m0]);
#pragma unroll
                for (int i = 0; i < 4; ++i)
#pragma unroll
                    for (int j = 0; j < 4; ++j)
#pragma unroll
                        for (int kk = 0; kk < 4; ++kk)
                            acc[i][j] += a_s[i][kk] * w_s[kk][j];
            }
        }
        __syncthreads();
    }

    float bv[4] = {0.f, 0.f, 0.f, 0.f};
    if (bias) {
#pragma unroll
        for (int j = 0; j < 4; ++j) bv[j] = bias[m0 + j];
    }
#pragma unroll
    for (int i = 0; i < 4; ++i) {
        int rw = nbase + n0 + i;
        if (rw < nrows) {
            float4 r;
            r.x = acc[i][0] + bv[0];
            r.y = acc[i][1] + bv[1];
            r.z = acc[i][2] + bv[2];
            r.w = acc[i][3] + bv[3];
            if (do_relu) {
                r.x = fmaxf(r.x, 0.f); r.y = fmaxf(r.y, 0.f);
                r.z = fmaxf(r.z, 0.f); r.w = fmaxf(r.w, 0.f);
            }
            *reinterpret_cast<float4*>(&out[(long long)rw * 128 + m0]) = r;
        }
    }
}

// ---------------- pooling: psum[g][f] += h[n][f], pcnt[g] += 1 (batch sorted) -------
__global__ __launch_bounds__(256) void gc_pool(const float* __restrict__ h,
                                               const int* __restrict__ batch,
                                               float* __restrict__ psum,
                                               float* __restrict__ pcnt, int n) {
    int base = blockIdx.x * 128;
    int sub = threadIdx.x >> 6;   // 0..3 -> 32 nodes each
    int fp = threadIdx.x & 63;    // feature pair
    int start = base + sub * 32;
    int end = min(start + 32, n);
    if (start >= end) return;
    int cur = batch[start];
    float s0 = 0.f, s1 = 0.f;
    int run = 0;
    for (int node = start; node < end; ++node) {
        int g = batch[node];
        if (g != cur) {
            unsafeAtomicAdd(&psum[cur * HID + fp * 2 + 0], s0);
            unsafeAtomicAdd(&psum[cur * HID + fp * 2 + 1], s1);
            if (fp == 0) unsafeAtomicAdd(&pcnt[cur], (float)run);
            s0 = s1 = 0.f; run = 0; cur = g;
        }
        float2 v = reinterpret_cast<const float2*>(h)[(long long)node * 64 + fp];
        s0 += v.x; s1 += v.y; ++run;
    }
    unsafeAtomicAdd(&psum[cur * HID + fp * 2 + 0], s0);
    unsafeAtomicAdd(&psum[cur * HID + fp * 2 + 1], s1);
    if (fp == 0) unsafeAtomicAdd(&pcnt[cur], (float)run);
}

// ---------------- xn = normalize(psum/cnt), one block per graph ----------------
__global__ __launch_bounds__(128) void gc_finalize_xn(const float* __restrict__ psum,
                                                      const float* __restrict__ pcnt,
                                                      float* __restrict__ xn) {
    int g = blockIdx.x;
    int f = threadIdx.x;
    float c = fmaxf(pcnt[g], 1.0f);
    float v = psum[g * HID + f] / c;
    float ss = v * v;
#pragma unroll
    for (int off = 32; off >= 1; off >>= 1) ss += __shfl_xor(ss, off, 64);
    __shared__ float s2[2];
    if ((threadIdx.x & 63) == 0) s2[threadIdx.x >> 6] = ss;
    __syncthreads();
    float denom = fmaxf(sqrtf(s2[0] + s2[1]), 1e-12f);
    xn[g * HID + f] = v / denom;
}

// ---------------- out = xn @ normalize(Wl).T + bl ----------------
__global__ __launch_bounds__(256) void gc_finalize_out(const float* __restrict__ xn,
                                                       const float* __restrict__ Wl,
                                                       const float* __restrict__ bl,
                                                       float* __restrict__ out,
                                                       int G, int C) {
    __shared__ float Wn[10][128];
    int wave = threadIdx.x >> 6, lane = threadIdx.x & 63;
    for (int r = wave; r < C; r += 4) {
        float v0 = Wl[r * 128 + lane * 2 + 0];
        float v1 = Wl[r * 128 + lane * 2 + 1];
        float ss = v0 * v0 + v1 * v1;
#pragma unroll
        for (int off = 32; off >= 1; off >>= 1) ss += __shfl_xor(ss, off, 64);
        float denom = fmaxf(sqrtf(ss), 1e-12f);
        Wn[r][lane * 2 + 0] = v0 / denom;
        Wn[r][lane * 2 + 1] = v1 / denom;
    }
    __syncthreads();
    for (int idx = threadIdx.x; idx < G * C; idx += 256) {
        int g = idx / C, c = idx % C;
        const float* xr = xn + g * HID;
        float acc = bl[c];
        for (int k = 0; k < HID; ++k) acc += xr[k] * Wn[c][k];
        out[idx] = acc;
    }
}

extern "C" void kernel_launch(void* const* d_in, const int* in_sizes, int n_in,
                              void* d_out, int out_size, void* d_ws, size_t ws_size,
                              hipStream_t stream) {
    const float* x      = (const float*)d_in[0];
    const int*   ei     = (const int*)d_in[1];
    const int*   batch  = (const int*)d_in[2];
    const float* W1_rel = (const float*)d_in[3];
    const float* b1     = (const float*)d_in[4];
    const float* W1_root= (const float*)d_in[5];
    const float* W2     = (const float*)d_in[6];
    const float* b2     = (const float*)d_in[7];
    const float* W3     = (const float*)d_in[8];
    const float* b3     = (const float*)d_in[9];
    const float* Wl     = (const float*)d_in[10];
    const float* bl     = (const float*)d_in[11];

    const int N = in_sizes[0] / HID;       // 50000
    const int E = in_sizes[1] / 2;         // 800000
    const int C = 10;
    const int G = out_size / (HID + C);    // 128

    const int* row = ei;
    const int* col = ei + E;

    float* buf0 = (float*)d_ws;                       // N*128
    float* buf1 = buf0 + (size_t)N * HID;             // N*128
    float* dinv = buf1 + (size_t)N * HID;             // N
    float* psum = dinv + N;                           // G*128
    float* pcnt = psum + (size_t)G * HID;             // G

    float* xn   = (float*)d_out;                      // G*128
    float* outp = xn + (size_t)G * HID;               // G*C

    const int eb = (int)(((long long)E * 32 + 255) / 256);
    const int nb32 = (N * 32 + 255) / 256;
    const int gb = (N + 31) / 32;

    // init accumulators
    hipMemsetAsync(buf0, 0, (size_t)N * HID * sizeof(float), stream);
    hipMemsetAsync(dinv, 0, (size_t)N * sizeof(float), stream);
    hipMemsetAsync(psum, 0, (size_t)(G * HID + G) * sizeof(float), stream);

    // degree -> dinv
    gc_deg_count<<<(E + 255) / 256, 256, 0, stream>>>(col, dinv, E);
    gc_deg_finish<<<(N + 255) / 256, 256, 0, stream>>>(dinv, N);

    // conv1: agg = scatter(x); h = relu(agg@W1_rel.T + x@W1_root.T + b1)
    gc_edge_scatter<<<eb, 256, 0, stream>>>(row, col, x, nullptr, buf0, E);
    gc_gemm128<<<gb, 256, 0, stream>>>(buf0, W1_rel, x, W1_root, b1, buf1, N, 1);

    // conv2: hp = h@W2.T; h2 = relu(scatter(hp*norm) + hp*dinv^2 + b2)
    gc_gemm128<<<gb, 256, 0, stream>>>(buf1, W2, nullptr, nullptr, nullptr, buf0, N, 0);
    hipMemsetAsync(buf1, 0, (size_t)N * HID * sizeof(float), stream);
    gc_edge_scatter<<<eb, 256, 0, stream>>>(row, col, buf0, dinv, buf1, E);
    gc_self_bias<<<nb32, 256, 0, stream>>>(buf1, buf0, dinv, b2, N, 1);

    // conv3: same, no relu
    gc_gemm128<<<gb, 256, 0, stream>>>(buf1, W3, nullptr, nullptr, nullptr, buf0, N, 0);
    hipMemsetAsync(buf1, 0, (size_t)N * HID * sizeof(float), stream);
    gc_edge_scatter<<<eb, 256, 0, stream>>>(row, col, buf0, dinv, buf1, E);
    gc_self_bias<<<nb32, 256, 0, stream>>>(buf1, buf0, dinv, b3, N, 0);

    // pool + normalize head
    gc_pool<<<(N + 127) / 128, 256, 0, stream>>>(buf1, batch, psum, pcnt, N);
    gc_finalize_xn<<<G, 128, 0, stream>>>(psum, pcnt, xn);
    gc_finalize_out<<<1, 256, 0, stream>>>(xn, Wl, bl, outp, G, C);
}

// Round 2
// 783.644 us; speedup vs baseline: 5.8006x; 5.8006x over previous
//
#include <hip/hip_runtime.h>

#define HID 128

// ---------------- degree histogram (int) ----------------
__global__ __launch_bounds__(256) void gc_deg_count(const int* __restrict__ col,
                                                    int* __restrict__ deg, int E) {
    int e = blockIdx.x * 256 + threadIdx.x;
    if (e < E) atomicAdd(&deg[col[e]], 1);
}

__global__ __launch_bounds__(256) void gc_dinv(const int* __restrict__ deg,
                                               float* __restrict__ dinv, int n) {
    int i = blockIdx.x * 256 + threadIdx.x;
    if (i < n) dinv[i] = rsqrtf((float)deg[i] + 1.0f);  // +1 for self-loop
}

// ---------------- single-block exclusive scan: offs[0..n], offs[n]=total -------------
__global__ __launch_bounds__(1024) void gc_scan(const int* __restrict__ deg,
                                                int* __restrict__ offs, int n) {
    __shared__ int tsum[1024];
    const int t = threadIdx.x;
    const int chunk = (n + 1023) / 1024;
    const int s = t * chunk;
    const int e = min(s + chunk, n);
    int acc = 0;
    for (int i = s; i < e; ++i) acc += deg[i];
    tsum[t] = acc;
    __syncthreads();
    for (int off = 1; off < 1024; off <<= 1) {
        int v = (t >= off) ? tsum[t - off] : 0;
        __syncthreads();
        tsum[t] += v;
        __syncthreads();
    }
    int base = (t == 0) ? 0 : tsum[t - 1];
    for (int i = s; i < e; ++i) { offs[i] = base; base += deg[i]; }
    if (t == 1023) offs[n] = base;
}

// ---------------- bucket fill: eid[slot] = src node, grouped by dst ----------------
__global__ __launch_bounds__(256) void gc_fill(const int* __restrict__ row,
                                               const int* __restrict__ col,
                                               int* __restrict__ cursor,
                                               int* __restrict__ eid, int E) {
    int e = blockIdx.x * 256 + threadIdx.x;
    if (e < E) {
        int pos = atomicAdd(&cursor[col[e]], 1);
        eid[pos] = row[e];
    }
}

// ---------------- gather-aggregate: one half-wave (32 lanes x float4) per dst node --
__global__ __launch_bounds__(256) void gc_gather(const int* __restrict__ offs,
                                                 const int* __restrict__ eid,
                                                 const float* __restrict__ src,
                                                 const float* __restrict__ dinv,
                                                 const float* __restrict__ selfh,
                                                 const float* __restrict__ bias,
                                                 float* __restrict__ dst,
                                                 int n, int do_relu) {
    int node = (blockIdx.x * 256 + threadIdx.x) >> 5;
    if (node >= n) return;
    const int c = threadIdx.x & 31;
    const int s = offs[node], e = offs[node + 1];
    const bool use_norm = (dinv != nullptr);
    const float ddst = use_norm ? dinv[node] : 1.0f;
    const float4* __restrict__ src4 = reinterpret_cast<const float4*>(src);

    float4 acc = make_float4(0.f, 0.f, 0.f, 0.f);
    int j = s;
    for (; j + 1 < e; j += 2) {
        int r0 = eid[j], r1 = eid[j + 1];
        float s0 = use_norm ? dinv[r0] * ddst : 1.0f;
        float s1 = use_norm ? dinv[r1] * ddst : 1.0f;
        float4 v0 = src4[(long long)r0 * 32 + c];
        float4 v1 = src4[(long long)r1 * 32 + c];
        acc.x += v0.x * s0 + v1.x * s1;
        acc.y += v0.y * s0 + v1.y * s1;
        acc.z += v0.z * s0 + v1.z * s1;
        acc.w += v0.w * s0 + v1.w * s1;
    }
    if (j < e) {
        int r0 = eid[j];
        float s0 = use_norm ? dinv[r0] * ddst : 1.0f;
        float4 v0 = src4[(long long)r0 * 32 + c];
        acc.x += v0.x * s0;
        acc.y += v0.y * s0;
        acc.z += v0.z * s0;
        acc.w += v0.w * s0;
    }
    if (selfh) {
        float di2 = ddst * ddst;
        float4 h = reinterpret_cast<const float4*>(selfh)[(long long)node * 32 + c];
        acc.x += h.x * di2 + bias[c * 4 + 0];
        acc.y += h.y * di2 + bias[c * 4 + 1];
        acc.z += h.z * di2 + bias[c * 4 + 2];
        acc.w += h.w * di2 + bias[c * 4 + 3];
        if (do_relu) {
            acc.x = fmaxf(acc.x, 0.f); acc.y = fmaxf(acc.y, 0.f);
            acc.z = fmaxf(acc.z, 0.f); acc.w = fmaxf(acc.w, 0.f);
        }
    }
    reinterpret_cast<float4*>(dst)[(long long)node * 32 + c] = acc;
}

// ---------------- GEMM: out[n][m] = (A1@W1.T)[n][m] (+ A2@W2.T) (+bias) (relu) ------
__global__ __launch_bounds__(256) void gc_gemm128(const float* __restrict__ A1,
                                                  const float* __restrict__ W1,
                                                  const float* __restrict__ A2,
                                                  const float* __restrict__ W2,
                                                  const float* __restrict__ bias,
                                                  float* __restrict__ out,
                                                  int nrows, int do_relu) {
    __shared__ __attribute__((aligned(16))) float Wt[2][32][132];  // [mat][k][m]
    __shared__ __attribute__((aligned(16))) float As[2][32][36];   // [mat][r][k]
    const int tx = threadIdx.x;
    const int nbase = blockIdx.x * 32;
    const int n0 = (tx >> 5) * 4;
    const int m0 = (tx & 31) * 4;
    const bool dual = (A2 != nullptr);

    float acc[4][4];
#pragma unroll
    for (int i = 0; i < 4; ++i)
#pragma unroll
        for (int j = 0; j < 4; ++j) acc[i][j] = 0.f;

    for (int kt = 0; kt < 128; kt += 32) {
#pragma unroll
        for (int i = 0; i < 16; ++i) {
            int idx = i * 256 + tx;
            int m = idx >> 5, k = idx & 31;
            Wt[0][k][m] = W1[m * 128 + kt + k];
        }
        if (dual) {
#pragma unroll
            for (int i = 0; i < 16; ++i) {
                int idx = i * 256 + tx;
                int m = idx >> 5, k = idx & 31;
                Wt[1][k][m] = W2[m * 128 + kt + k];
            }
        }
#pragma unroll
        for (int i = 0; i < 4; ++i) {
            int idx = i * 256 + tx;
            int r = idx >> 5, k = idx & 31;
            int rw = nbase + r;
            As[0][r][k] = (rw < nrows) ? A1[(long long)rw * 128 + kt + k] : 0.f;
        }
        if (dual) {
#pragma unroll
            for (int i = 0; i < 4; ++i) {
                int idx = i * 256 + tx;
                int r = idx >> 5, k = idx & 31;
                int rw = nbase + r;
                As[1][r][k] = (rw < nrows) ? A2[(long long)rw * 128 + kt + k] : 0.f;
            }
        }
        __syncthreads();

        for (int mat = 0; mat < (dual ? 2 : 1); ++mat) {
#pragma unroll
            for (int k = 0; k < 32; k += 4) {
                float a_s[4][4], w_s[4][4];
#pragma unroll
                for (int i = 0; i < 4; ++i)
                    *reinterpret_cast<float4*>(a_s[i]) =
                        *reinterpret_cast<const float4*>(&As[mat][n0 + i][k]);
#pragma unroll
                for (int kk = 0; kk < 4; ++kk)
                    *reinterpret_cast<float4*>(w_s[kk]) =
                        *reinterpret_cast<const float4*>(&Wt[mat][k + kk][m0]);
#pragma unroll
                for (int i = 0; i < 4; ++i)
#pragma unroll
                    for (int j = 0; j < 4; ++j)
#pragma unroll
                        for (int kk = 0; kk < 4; ++kk)
                            acc[i][j] += a_s[i][kk] * w_s[kk][j];
            }
        }
        __syncthreads();
    }

    float bv[4] = {0.f, 0.f, 0.f, 0.f};
    if (bias) {
#pragma unroll
        for (int j = 0; j < 4; ++j) bv[j] = bias[m0 + j];
    }
#pragma unroll
    for (int i = 0; i < 4; ++i) {
        int rw = nbase + n0 + i;
        if (rw < nrows) {
            float4 r;
            r.x = acc[i][0] + bv[0];
            r.y = acc[i][1] + bv[1];
            r.z = acc[i][2] + bv[2];
            r.w = acc[i][3] + bv[3];
            if (do_relu) {
                r.x = fmaxf(r.x, 0.f); r.y = fmaxf(r.y, 0.f);
                r.z = fmaxf(r.z, 0.f); r.w = fmaxf(r.w, 0.f);
            }
            *reinterpret_cast<float4*>(&out[(long long)rw * 128 + m0]) = r;
        }
    }
}

// ---------------- pooling (batch sorted): run-length accumulate then atomic flush ---
__global__ __launch_bounds__(256) void gc_pool(const float* __restrict__ h,
                                               const int* __restrict__ batch,
                                               float* __restrict__ psum,
                                               float* __restrict__ pcnt, int n) {
    int base = blockIdx.x * 128;
    int sub = threadIdx.x >> 6;
    int fp = threadIdx.x & 63;
    int start = base + sub * 32;
    int end = min(start + 32, n);
    if (start >= end) return;
    int cur = batch[start];
    float s0 = 0.f, s1 = 0.f;
    int run = 0;
    for (int node = start; node < end; ++node) {
        int g = batch[node];
        if (g != cur) {
            unsafeAtomicAdd(&psum[cur * HID + fp * 2 + 0], s0);
            unsafeAtomicAdd(&psum[cur * HID + fp * 2 + 1], s1);
            if (fp == 0) unsafeAtomicAdd(&pcnt[cur], (float)run);
            s0 = s1 = 0.f; run = 0; cur = g;
        }
        float2 v = reinterpret_cast<const float2*>(h)[(long long)node * 64 + fp];
        s0 += v.x; s1 += v.y; ++run;
    }
    unsafeAtomicAdd(&psum[cur * HID + fp * 2 + 0], s0);
    unsafeAtomicAdd(&psum[cur * HID + fp * 2 + 1], s1);
    if (fp == 0) unsafeAtomicAdd(&pcnt[cur], (float)run);
}

// ---------------- xn = normalize(psum/cnt), one block per graph ----------------
__global__ __launch_bounds__(128) void gc_finalize_xn(const float* __restrict__ psum,
                                                      const float* __restrict__ pcnt,
                                                      float* __restrict__ xn) {
    int g = blockIdx.x;
    int f = threadIdx.x;
    float c = fmaxf(pcnt[g], 1.0f);
    float v = psum[g * HID + f] / c;
    float ss = v * v;
#pragma unroll
    for (int off = 32; off >= 1; off >>= 1) ss += __shfl_xor(ss, off, 64);
    __shared__ float s2[2];
    if ((threadIdx.x & 63) == 0) s2[threadIdx.x >> 6] = ss;
    __syncthreads();
    float denom = fmaxf(sqrtf(s2[0] + s2[1]), 1e-12f);
    xn[g * HID + f] = v / denom;
}

// ---------------- out = xn @ normalize(Wl).T + bl ----------------
__global__ __launch_bounds__(256) void gc_finalize_out(const float* __restrict__ xn,
                                                       const float* __restrict__ Wl,
                                                       const float* __restrict__ bl,
                                                       float* __restrict__ out,
                                                       int G, int C) {
    __shared__ float Wn[10][128];
    int wave = threadIdx.x >> 6, lane = threadIdx.x & 63;
    for (int r = wave; r < C; r += 4) {
        float v0 = Wl[r * 128 + lane * 2 + 0];
        float v1 = Wl[r * 128 + lane * 2 + 1];
        float ss = v0 * v0 + v1 * v1;
#pragma unroll
        for (int off = 32; off >= 1; off >>= 1) ss += __shfl_xor(ss, off, 64);
        float denom = fmaxf(sqrtf(ss), 1e-12f);
        Wn[r][lane * 2 + 0] = v0 / denom;
        Wn[r][lane * 2 + 1] = v1 / denom;
    }
    __syncthreads();
    for (int idx = threadIdx.x; idx < G * C; idx += 256) {
        int g = idx / C, c = idx % C;
        const float* xr = xn + g * HID;
        float acc = bl[c];
        for (int k = 0; k < HID; ++k) acc += xr[k] * Wn[c][k];
        out[idx] = acc;
    }
}

extern "C" void kernel_launch(void* const* d_in, const int* in_sizes, int n_in,
                              void* d_out, int out_size, void* d_ws, size_t ws_size,
                              hipStream_t stream) {
    const float* x      = (const float*)d_in[0];
    const int*   ei     = (const int*)d_in[1];
    const int*   batch  = (const int*)d_in[2];
    const float* W1_rel = (const float*)d_in[3];
    const float* b1     = (const float*)d_in[4];
    const float* W1_root= (const float*)d_in[5];
    const float* W2     = (const float*)d_in[6];
    const float* b2     = (const float*)d_in[7];
    const float* W3     = (const float*)d_in[8];
    const float* b3     = (const float*)d_in[9];
    const float* Wl     = (const float*)d_in[10];
    const float* bl     = (const float*)d_in[11];

    const int N = in_sizes[0] / HID;       // 50000
    const int E = in_sizes[1] / 2;         // 800000
    const int C = 10;
    const int G = out_size / (HID + C);    // 128

    const int* row = ei;
    const int* col = ei + E;

    float* buf0 = (float*)d_ws;                       // N*128
    float* buf1 = buf0 + (size_t)N * HID;             // N*128
    float* dinv = buf1 + (size_t)N * HID;             // N
    float* psum = dinv + N;                           // G*128
    float* pcnt = psum + (size_t)G * HID;             // G
    int*   degi = (int*)(pcnt + G);                   // N
    int*   offs = degi + N;                           // N+1
    int*   curs = offs + N + 1;                       // N
    int*   eid  = curs + N;                           // E

    float* xn   = (float*)d_out;                      // G*128
    float* outp = xn + (size_t)G * HID;               // G*C

    const int eb256 = (E + 255) / 256;
    const int nb256 = (N + 255) / 256;
    const int hwb   = (N * 32 + 255) / 256;
    const int gb    = (N + 31) / 32;

    // ---- build CSR by destination ----
    hipMemsetAsync(degi, 0, (size_t)N * sizeof(int), stream);
    hipMemsetAsync(psum, 0, (size_t)(G * HID + G) * sizeof(float), stream);
    gc_deg_count<<<eb256, 256, 0, stream>>>(col, degi, E);
    gc_scan<<<1, 1024, 0, stream>>>(degi, offs, N);
    hipMemcpyAsync(curs, offs, (size_t)N * sizeof(int), hipMemcpyDeviceToDevice, stream);
    gc_fill<<<eb256, 256, 0, stream>>>(row, col, curs, eid, E);
    gc_dinv<<<nb256, 256, 0, stream>>>(degi, dinv, N);

    // conv1
    gc_gather<<<hwb, 256, 0, stream>>>(offs, eid, x, nullptr, nullptr, nullptr, buf0, N, 0);
    gc_gemm128<<<gb, 256, 0, stream>>>(buf0, W1_rel, x, W1_root, b1, buf1, N, 1);

    // conv2
    gc_gemm128<<<gb, 256, 0, stream>>>(buf1, W2, nullptr, nullptr, nullptr, buf0, N, 0);
    gc_gather<<<hwb, 256, 0, stream>>>(offs, eid, buf0, dinv, buf0, b2, buf1, N, 1);

    // conv3
    gc_gemm128<<<gb, 256, 0, stream>>>(buf1, W3, nullptr, nullptr, nullptr, buf0, N, 0);
    gc_gather<<<hwb, 256, 0, stream>>>(offs, eid, buf0, dinv, buf0, b3, buf1, N, 0);

    // pool + head
    gc_pool<<<(N + 127) / 128, 256, 0, stream>>>(buf1, batch, psum, pcnt, N);
    gc_finalize_xn<<<G, 128, 0, stream>>>(psum, pcnt, xn);
    gc_finalize_out<<<1, 256, 0, stream>>>(xn, Wl, bl, outp, G, C);
}

// Round 4
// 454.282 us; speedup vs baseline: 10.0061x; 1.7250x over previous
//
#include <hip/hip_runtime.h>

#define HID 128

typedef __attribute__((ext_vector_type(8))) short short8;
typedef __attribute__((ext_vector_type(4))) float f32x4;

__device__ inline ushort f2b(float f) {
    union { float f; uint u; } v; v.f = f;
    uint u = v.u;
    return (ushort)((u + 0x7fffu + ((u >> 16) & 1u)) >> 16);  // RNE
}

__device__ inline void fma8(float* acc, uint4 u, float s) {
    acc[0] += __uint_as_float(u.x << 16) * s;
    acc[1] += __uint_as_float(u.x & 0xffff0000u) * s;
    acc[2] += __uint_as_float(u.y << 16) * s;
    acc[3] += __uint_as_float(u.y & 0xffff0000u) * s;
    acc[4] += __uint_as_float(u.z << 16) * s;
    acc[5] += __uint_as_float(u.z & 0xffff0000u) * s;
    acc[6] += __uint_as_float(u.w << 16) * s;
    acc[7] += __uint_as_float(u.w & 0xffff0000u) * s;
}

// ---------------- CSR build ----------------
__global__ __launch_bounds__(256) void gc_deg_count(const int* __restrict__ col,
                                                    int* __restrict__ deg, int E) {
    int e = blockIdx.x * 256 + threadIdx.x;
    if (e < E) atomicAdd(&deg[col[e]], 1);
}

__global__ __launch_bounds__(256) void gc_dinv(const int* __restrict__ deg,
                                               float* __restrict__ dinv, int n) {
    int i = blockIdx.x * 256 + threadIdx.x;
    if (i < n) dinv[i] = rsqrtf((float)deg[i] + 1.0f);  // +1 self-loop
}

__global__ __launch_bounds__(1024) void gc_scan(const int* __restrict__ deg,
                                                int* __restrict__ offs, int n) {
    __shared__ int tsum[1024];
    const int t = threadIdx.x;
    const int chunk = (n + 1023) / 1024;
    const int s = t * chunk;
    const int e = min(s + chunk, n);
    int acc = 0;
    for (int i = s; i < e; ++i) acc += deg[i];
    tsum[t] = acc;
    __syncthreads();
    for (int off = 1; off < 1024; off <<= 1) {
        int v = (t >= off) ? tsum[t - off] : 0;
        __syncthreads();
        tsum[t] += v;
        __syncthreads();
    }
    int base = (t == 0) ? 0 : tsum[t - 1];
    for (int i = s; i < e; ++i) { offs[i] = base; base += deg[i]; }
    if (t == 1023) offs[n] = base;
}

__global__ __launch_bounds__(256) void gc_fill(const int* __restrict__ row,
                                               const int* __restrict__ col,
                                               int* __restrict__ cursor,
                                               int* __restrict__ eid, int E) {
    int e = blockIdx.x * 256 + threadIdx.x;
    if (e < E) {
        int pos = atomicAdd(&cursor[col[e]], 1);
        eid[pos] = row[e];
    }
}

// ---------------- fp32 -> bf16 conversion (8 elems/thread) ----------------
__global__ __launch_bounds__(256) void gc_cvt(const float* __restrict__ src,
                                              ushort* __restrict__ dst, int n8) {
    int i = blockIdx.x * 256 + threadIdx.x;
    if (i >= n8) return;
    const float4* s4 = (const float4*)src;
    float4 a = s4[i * 2], b = s4[i * 2 + 1];
    uint4 o;
    o.x = (uint)f2b(a.x) | ((uint)f2b(a.y) << 16);
    o.y = (uint)f2b(a.z) | ((uint)f2b(a.w) << 16);
    o.z = (uint)f2b(b.x) | ((uint)f2b(b.y) << 16);
    o.w = (uint)f2b(b.z) | ((uint)f2b(b.w) << 16);
    ((uint4*)dst)[i] = o;
}

// ---------------- gather (bf16 in/out, fp32 accumulate) ----------------
// 16 lanes per node, 16B (8 bf16) per lane.
__global__ __launch_bounds__(256) void gc_gather_b(const int* __restrict__ offs,
                                                   const int* __restrict__ eid,
                                                   const ushort* __restrict__ src,
                                                   const float* __restrict__ dinv,
                                                   const ushort* __restrict__ selfh,
                                                   const float* __restrict__ bias,
                                                   ushort* __restrict__ dst,
                                                   int n, int do_relu) {
    int node = (blockIdx.x * 256 + threadIdx.x) >> 4;
    if (node >= n) return;
    const int c = threadIdx.x & 15;
    const int s = offs[node], e = offs[node + 1];
    const bool un = (dinv != nullptr);
    const float dd = un ? dinv[node] : 1.0f;
    const uint4* __restrict__ src4 = (const uint4*)src;  // 16 uint4 per row

    float acc[8];
#pragma unroll
    for (int k = 0; k < 8; ++k) acc[k] = 0.f;

    int j = s;
    for (; j + 1 < e; j += 2) {
        int r0 = eid[j], r1 = eid[j + 1];
        float s0 = un ? dinv[r0] * dd : 1.0f;
        float s1 = un ? dinv[r1] * dd : 1.0f;
        uint4 u0 = src4[(size_t)r0 * 16 + c];
        uint4 u1 = src4[(size_t)r1 * 16 + c];
        fma8(acc, u0, s0);
        fma8(acc, u1, s1);
    }
    if (j < e) {
        int r0 = eid[j];
        float s0 = un ? dinv[r0] * dd : 1.0f;
        fma8(acc, src4[(size_t)r0 * 16 + c], s0);
    }
    if (selfh) {
        float di2 = dd * dd;
        fma8(acc, ((const uint4*)selfh)[(size_t)node * 16 + c], di2);
#pragma unroll
        for (int k = 0; k < 8; ++k) acc[k] += bias[c * 8 + k];
    }
    if (do_relu) {
#pragma unroll
        for (int k = 0; k < 8; ++k) acc[k] = fmaxf(acc[k], 0.f);
    }
    uint4 o;
    o.x = (uint)f2b(acc[0]) | ((uint)f2b(acc[1]) << 16);
    o.y = (uint)f2b(acc[2]) | ((uint)f2b(acc[3]) << 16);
    o.z = (uint)f2b(acc[4]) | ((uint)f2b(acc[5]) << 16);
    o.w = (uint)f2b(acc[6]) | ((uint)f2b(acc[7]) << 16);
    ((uint4*)dst)[(size_t)node * 16 + c] = o;
}

// ---------------- MFMA GEMM: out = A1@W1.T (+ A2@W2.T) (+bias) (relu), bf16 ----------
// 256 thr = 4 waves; wave computes 16 rows x 128 cols via 16x16x32 MFMA.
// W staged in LDS (row stride 136 bf16), A-frags direct from global.
__global__ __launch_bounds__(256) void gc_gemm_mfma(const ushort* __restrict__ A1,
                                                    const ushort* __restrict__ W1,
                                                    const ushort* __restrict__ A2,
                                                    const ushort* __restrict__ W2,
                                                    const float* __restrict__ bias,
                                                    ushort* __restrict__ out,
                                                    int nrows, int do_relu) {
    __shared__ ushort lds[128 * 136];  // 34816 B; epilogue reuses first 17408 B
    const int t = threadIdx.x;
    const int w = t >> 6;
    const int l = t & 63;
    const int lr = l & 15;   // A row in tile / B col in tile
    const int g = l >> 4;    // k-group
    const int row0 = blockIdx.x * 64 + w * 16;

    f32x4 acc[8];
#pragma unroll
    for (int i = 0; i < 8; ++i) acc[i] = (f32x4){0.f, 0.f, 0.f, 0.f};

    const int nmat = (A2 != nullptr) ? 2 : 1;
    for (int mat = 0; mat < nmat; ++mat) {
        const ushort* __restrict__ A = mat ? A2 : A1;
        const ushort* __restrict__ W = mat ? W2 : W1;
        __syncthreads();  // protect LDS reuse between mats (no-op first pass)
        // stage W: 128 rows x 16 chunks of 16B = 2048 chunks  (FIXED: was 1024/half-row)
#pragma unroll
        for (int i = 0; i < 8; ++i) {
            int cid = i * 256 + t;
            int r = cid >> 4, ch = cid & 15;
            *(uint4*)(&lds[r * 136 + ch * 8]) = ((const uint4*)W)[cid];
        }
        __syncthreads();

        short8 af[4];
        const int arow = row0 + lr;
        const bool ok = arow < nrows;
#pragma unroll
        for (int ks = 0; ks < 4; ++ks) {
            if (ok)
                af[ks] = *(const short8*)(A + (size_t)arow * 128 + ks * 32 + g * 8);
            else
                af[ks] = (short8){0, 0, 0, 0, 0, 0, 0, 0};
        }
#pragma unroll
        for (int ct = 0; ct < 8; ++ct) {
#pragma unroll
            for (int ks = 0; ks < 4; ++ks) {
                short8 bf = *(const short8*)(&lds[(ct * 16 + lr) * 136 + ks * 32 + g * 8]);
                acc[ct] = __builtin_amdgcn_mfma_f32_16x16x32_bf16(af[ks], bf, acc[ct], 0, 0, 0);
            }
        }
    }

    float bv[8];
#pragma unroll
    for (int ct = 0; ct < 8; ++ct) bv[ct] = bias ? bias[ct * 16 + lr] : 0.f;

    __syncthreads();  // all MFMA LDS reads done before epilogue reuse
    ushort* ep = &lds[w * (16 * 136)];
#pragma unroll
    for (int ct = 0; ct < 8; ++ct) {
#pragma unroll
        for (int r = 0; r < 4; ++r) {
            float v = acc[ct][r] + bv[ct];
            if (do_relu) v = fmaxf(v, 0.f);
            ep[(g * 4 + r) * 136 + ct * 16 + lr] = f2b(v);
        }
    }
    __syncthreads();  // order writes before cross-lane reads
#pragma unroll
    for (int i = 0; i < 4; ++i) {
        int rr = i * 4 + g;
        int grow = row0 + rr;
        if (grow < nrows) {
            uint4 vv = *(uint4*)(&ep[rr * 136 + lr * 8]);
            ((uint4*)out)[(size_t)grow * 16 + lr] = vv;
        }
    }
}

// ---------------- pooling (bf16 in, fp32 accumulate; batch sorted) ----------------
__global__ __launch_bounds__(256) void gc_pool(const ushort* __restrict__ h,
                                               const int* __restrict__ batch,
                                               float* __restrict__ psum,
                                               float* __restrict__ pcnt, int n) {
    int base = blockIdx.x * 128;
    int sub = threadIdx.x >> 6;
    int fp = threadIdx.x & 63;
    int start = base + sub * 32;
    int end = min(start + 32, n);
    if (start >= end) return;
    int cur = batch[start];
    float s0 = 0.f, s1 = 0.f;
    int run = 0;
    const uint* h2 = (const uint*)h;
    for (int node = start; node < end; ++node) {
        int g = batch[node];
        if (g != cur) {
            unsafeAtomicAdd(&psum[cur * HID + fp * 2 + 0], s0);
            unsafeAtomicAdd(&psum[cur * HID + fp * 2 + 1], s1);
            if (fp == 0) unsafeAtomicAdd(&pcnt[cur], (float)run);
            s0 = s1 = 0.f; run = 0; cur = g;
        }
        uint u = h2[(size_t)node * 64 + fp];
        s0 += __uint_as_float(u << 16);
        s1 += __uint_as_float(u & 0xffff0000u);
        ++run;
    }
    unsafeAtomicAdd(&psum[cur * HID + fp * 2 + 0], s0);
    unsafeAtomicAdd(&psum[cur * HID + fp * 2 + 1], s1);
    if (fp == 0) unsafeAtomicAdd(&pcnt[cur], (float)run);
}

// ---------------- xn = normalize(psum/cnt) ----------------
__global__ __launch_bounds__(128) void gc_finalize_xn(const float* __restrict__ psum,
                                                      const float* __restrict__ pcnt,
                                                      float* __restrict__ xn) {
    int g = blockIdx.x;
    int f = threadIdx.x;
    float c = fmaxf(pcnt[g], 1.0f);
    float v = psum[g * HID + f] / c;
    float ss = v * v;
#pragma unroll
    for (int off = 32; off >= 1; off >>= 1) ss += __shfl_xor(ss, off, 64);
    __shared__ float s2[2];
    if ((threadIdx.x & 63) == 0) s2[threadIdx.x >> 6] = ss;
    __syncthreads();
    float denom = fmaxf(sqrtf(s2[0] + s2[1]), 1e-12f);
    xn[g * HID + f] = v / denom;
}

// ---------------- out = xn @ normalize(Wl).T + bl ----------------
__global__ __launch_bounds__(256) void gc_finalize_out(const float* __restrict__ xn,
                                                       const float* __restrict__ Wl,
                                                       const float* __restrict__ bl,
                                                       float* __restrict__ out,
                                                       int G, int C) {
    __shared__ float Wn[10][128];
    int wave = threadIdx.x >> 6, lane = threadIdx.x & 63;
    for (int r = wave; r < C; r += 4) {
        float v0 = Wl[r * 128 + lane * 2 + 0];
        float v1 = Wl[r * 128 + lane * 2 + 1];
        float ss = v0 * v0 + v1 * v1;
#pragma unroll
        for (int off = 32; off >= 1; off >>= 1) ss += __shfl_xor(ss, off, 64);
        float denom = fmaxf(sqrtf(ss), 1e-12f);
        Wn[r][lane * 2 + 0] = v0 / denom;
        Wn[r][lane * 2 + 1] = v1 / denom;
    }
    __syncthreads();
    for (int idx = threadIdx.x; idx < G * C; idx += 256) {
        int g = idx / C, c = idx % C;
        const float* xr = xn + g * HID;
        float acc = bl[c];
        for (int k = 0; k < HID; ++k) acc += xr[k] * Wn[c][k];
        out[idx] = acc;
    }
}

extern "C" void kernel_launch(void* const* d_in, const int* in_sizes, int n_in,
                              void* d_out, int out_size, void* d_ws, size_t ws_size,
                              hipStream_t stream) {
    const float* x      = (const float*)d_in[0];
    const int*   ei     = (const int*)d_in[1];
    const int*   batch  = (const int*)d_in[2];
    const float* W1_rel = (const float*)d_in[3];
    const float* b1     = (const float*)d_in[4];
    const float* W1_root= (const float*)d_in[5];
    const float* W2     = (const float*)d_in[6];
    const float* b2     = (const float*)d_in[7];
    const float* W3     = (const float*)d_in[8];
    const float* b3     = (const float*)d_in[9];
    const float* Wl     = (const float*)d_in[10];
    const float* bl     = (const float*)d_in[11];

    const int N = in_sizes[0] / HID;     // 50000
    const int E = in_sizes[1] / 2;       // 800000
    const int C = 10;
    const int G = out_size / (HID + C);  // 128

    const int* row = ei;
    const int* col = ei + E;

    // workspace layout (16B alignment maintained)
    ushort* xb  = (ushort*)d_ws;                      // N*128 bf16
    ushort* hb0 = xb  + (size_t)N * HID;              // N*128 bf16
    ushort* hb1 = hb0 + (size_t)N * HID;              // N*128 bf16
    ushort* wb  = hb1 + (size_t)N * HID;              // 4*16384 bf16 weights
    float* dinv = (float*)(wb + 4 * 16384);           // N
    float* psum = dinv + N;                           // G*128
    float* pcnt = psum + (size_t)G * HID;             // G
    int*   degi = (int*)(pcnt + G);                   // N
    int*   offs = degi + N;                           // N+1
    int*   curs = offs + N + 1;                       // N
    int*   eid  = curs + N;                           // E

    float* xn   = (float*)d_out;
    float* outp = xn + (size_t)G * HID;

    const int eb256 = (E + 255) / 256;
    const int nb256 = (N + 255) / 256;
    const int gthb  = (N * 16 + 255) / 256;   // gather: 16 lanes/node
    const int gmb   = (N + 63) / 64;          // gemm: 64 rows/block

    // ---- CSR build + dinv ----
    hipMemsetAsync(degi, 0, (size_t)N * sizeof(int), stream);
    hipMemsetAsync(psum, 0, (size_t)(G * HID + G) * sizeof(float), stream);
    gc_deg_count<<<eb256, 256, 0, stream>>>(col, degi, E);
    gc_scan<<<1, 1024, 0, stream>>>(degi, offs, N);
    hipMemcpyAsync(curs, offs, (size_t)N * sizeof(int), hipMemcpyDeviceToDevice, stream);
    gc_fill<<<eb256, 256, 0, stream>>>(row, col, curs, eid, E);
    gc_dinv<<<nb256, 256, 0, stream>>>(degi, dinv, N);

    // ---- conversions ----
    gc_cvt<<<(N * HID / 8 + 255) / 256, 256, 0, stream>>>(x, xb, N * HID / 8);
    gc_cvt<<<8, 256, 0, stream>>>(W1_rel,  wb,             2048);
    gc_cvt<<<8, 256, 0, stream>>>(W1_root, wb + 16384,     2048);
    gc_cvt<<<8, 256, 0, stream>>>(W2,      wb + 2 * 16384, 2048);
    gc_cvt<<<8, 256, 0, stream>>>(W3,      wb + 3 * 16384, 2048);

    // conv1: agg = gather(x); h1 = relu(agg@W1_rel.T + x@W1_root.T + b1)
    gc_gather_b<<<gthb, 256, 0, stream>>>(offs, eid, xb, nullptr, nullptr, nullptr, hb0, N, 0);
    gc_gemm_mfma<<<gmb, 256, 0, stream>>>(hb0, wb, xb, wb + 16384, b1, hb1, N, 1);

    // conv2: hp2 = h1@W2.T; h2 = relu(gatherN(hp2) + hp2*dinv^2 + b2)
    gc_gemm_mfma<<<gmb, 256, 0, stream>>>(hb1, wb + 2 * 16384, nullptr, nullptr, nullptr, hb0, N, 0);
    gc_gather_b<<<gthb, 256, 0, stream>>>(offs, eid, hb0, dinv, hb0, b2, hb1, N, 1);

    // conv3: hp3 = h2@W3.T; h3 = gatherN(hp3) + hp3*dinv^2 + b3
    gc_gemm_mfma<<<gmb, 256, 0, stream>>>(hb1, wb + 3 * 16384, nullptr, nullptr, nullptr, hb0, N, 0);
    gc_gather_b<<<gthb, 256, 0, stream>>>(offs, eid, hb0, dinv, hb0, b3, hb1, N, 0);

    // pool + head
    gc_pool<<<(N + 127) / 128, 256, 0, stream>>>(hb1, batch, psum, pcnt, N);
    gc_finalize_xn<<<G, 128, 0, stream>>>(psum, pcnt, xn);
    gc_finalize_out<<<1, 256, 0, stream>>>(xn, Wl, bl, outp, G, C);
}

// Round 5
// 380.579 us; speedup vs baseline: 11.9438x; 1.1937x over previous
//
#include <hip/hip_runtime.h>

#define HID 128

typedef __attribute__((ext_vector_type(8))) short short8;
typedef __attribute__((ext_vector_type(4))) float f32x4;

__device__ inline ushort f2b(float f) {
    union { float f; uint u; } v; v.f = f;
    uint u = v.u;
    return (ushort)((u + 0x7fffu + ((u >> 16) & 1u)) >> 16);  // RNE
}

__device__ inline void fma8(float* acc, uint4 u, float s) {
    acc[0] += __uint_as_float(u.x << 16) * s;
    acc[1] += __uint_as_float(u.x & 0xffff0000u) * s;
    acc[2] += __uint_as_float(u.y << 16) * s;
    acc[3] += __uint_as_float(u.y & 0xffff0000u) * s;
    acc[4] += __uint_as_float(u.z << 16) * s;
    acc[5] += __uint_as_float(u.z & 0xffff0000u) * s;
    acc[6] += __uint_as_float(u.w << 16) * s;
    acc[7] += __uint_as_float(u.w & 0xffff0000u) * s;
}

// ---------------- CSR build ----------------
__global__ __launch_bounds__(256) void gc_deg_count(const int* __restrict__ col,
                                                    int* __restrict__ deg, int E) {
    int e = blockIdx.x * 256 + threadIdx.x;
    if (e < E) atomicAdd(&deg[col[e]], 1);
}

__global__ __launch_bounds__(256) void gc_dinv(const int* __restrict__ deg,
                                               float* __restrict__ dinv, int n) {
    int i = blockIdx.x * 256 + threadIdx.x;
    if (i < n) dinv[i] = rsqrtf((float)deg[i] + 1.0f);  // +1 self-loop
}

// ---- multi-block exclusive scan: part-sums -> top scan -> final ----
__global__ __launch_bounds__(256) void gc_scan_part(const int* __restrict__ deg,
                                                    int* __restrict__ bsum, int n) {
    __shared__ int s[4];
    int i = blockIdx.x * 256 + threadIdx.x;
    int v = (i < n) ? deg[i] : 0;
#pragma unroll
    for (int off = 32; off >= 1; off >>= 1) v += __shfl_xor(v, off, 64);
    if ((threadIdx.x & 63) == 0) s[threadIdx.x >> 6] = v;
    __syncthreads();
    if (threadIdx.x == 0) bsum[blockIdx.x] = s[0] + s[1] + s[2] + s[3];
}

__global__ __launch_bounds__(256) void gc_scan_top(int* __restrict__ bsum, int B) {
    __shared__ int s[256];
    int t = threadIdx.x;
    int v = (t < B) ? bsum[t] : 0;
    s[t] = v;
    __syncthreads();
    for (int off = 1; off < 256; off <<= 1) {
        int u = (t >= off) ? s[t - off] : 0;
        __syncthreads();
        s[t] += u;
        __syncthreads();
    }
    int excl = (t == 0) ? 0 : s[t - 1];
    if (t < B) bsum[t] = excl;
}

__global__ __launch_bounds__(256) void gc_scan_final(const int* __restrict__ deg,
                                                     const int* __restrict__ bsum,
                                                     int* __restrict__ offs,
                                                     int* __restrict__ curs, int n) {
    __shared__ int s[256];
    int t = threadIdx.x;
    int i = blockIdx.x * 256 + t;
    int v = (i < n) ? deg[i] : 0;
    s[t] = v;
    __syncthreads();
    for (int off = 1; off < 256; off <<= 1) {
        int u = (t >= off) ? s[t - off] : 0;
        __syncthreads();
        s[t] += u;
        __syncthreads();
    }
    int excl = ((t == 0) ? 0 : s[t - 1]) + bsum[blockIdx.x];
    if (i < n) {
        offs[i] = excl;
        curs[i] = excl;
        if (i == n - 1) offs[n] = excl + v;
    }
}

__global__ __launch_bounds__(256) void gc_fill(const int* __restrict__ row,
                                               const int* __restrict__ col,
                                               int* __restrict__ cursor,
                                               int* __restrict__ eid, int E) {
    int e = blockIdx.x * 256 + threadIdx.x;
    if (e < E) {
        int pos = atomicAdd(&cursor[col[e]], 1);
        eid[pos] = row[e];
    }
}

// ---------------- fp32 -> bf16 conversion (8 elems/thread) ----------------
__global__ __launch_bounds__(256) void gc_cvt(const float* __restrict__ src,
                                              ushort* __restrict__ dst, int n8) {
    int i = blockIdx.x * 256 + threadIdx.x;
    if (i >= n8) return;
    const float4* s4 = (const float4*)src;
    float4 a = s4[i * 2], b = s4[i * 2 + 1];
    uint4 o;
    o.x = (uint)f2b(a.x) | ((uint)f2b(a.y) << 16);
    o.y = (uint)f2b(a.z) | ((uint)f2b(a.w) << 16);
    o.z = (uint)f2b(b.x) | ((uint)f2b(b.y) << 16);
    o.w = (uint)f2b(b.z) | ((uint)f2b(b.w) << 16);
    ((uint4*)dst)[i] = o;
}

// ---------------- gather (bf16 in/out, fp32 accumulate) ----------------
// 16 lanes per node, 16B (8 bf16) per lane.
__global__ __launch_bounds__(256) void gc_gather_b(const int* __restrict__ offs,
                                                   const int* __restrict__ eid,
                                                   const ushort* __restrict__ src,
                                                   const float* __restrict__ dinv,
                                                   const ushort* __restrict__ selfh,
                                                   const float* __restrict__ bias,
                                                   ushort* __restrict__ dst,
                                                   int n, int do_relu) {
    int node = (blockIdx.x * 256 + threadIdx.x) >> 4;
    if (node >= n) return;
    const int c = threadIdx.x & 15;
    const int s = offs[node], e = offs[node + 1];
    const bool un = (dinv != nullptr);
    const float dd = un ? dinv[node] : 1.0f;
    const uint4* __restrict__ src4 = (const uint4*)src;  // 16 uint4 per row

    float acc[8];
#pragma unroll
    for (int k = 0; k < 8; ++k) acc[k] = 0.f;

    int j = s;
    for (; j + 1 < e; j += 2) {
        int r0 = eid[j], r1 = eid[j + 1];
        float s0 = un ? dinv[r0] * dd : 1.0f;
        float s1 = un ? dinv[r1] * dd : 1.0f;
        uint4 u0 = src4[(size_t)r0 * 16 + c];
        uint4 u1 = src4[(size_t)r1 * 16 + c];
        fma8(acc, u0, s0);
        fma8(acc, u1, s1);
    }
    if (j < e) {
        int r0 = eid[j];
        float s0 = un ? dinv[r0] * dd : 1.0f;
        fma8(acc, src4[(size_t)r0 * 16 + c], s0);
    }
    if (selfh) {
        float di2 = dd * dd;
        fma8(acc, ((const uint4*)selfh)[(size_t)node * 16 + c], di2);
#pragma unroll
        for (int k = 0; k < 8; ++k) acc[k] += bias[c * 8 + k];
    }
    if (do_relu) {
#pragma unroll
        for (int k = 0; k < 8; ++k) acc[k] = fmaxf(acc[k], 0.f);
    }
    uint4 o;
    o.x = (uint)f2b(acc[0]) | ((uint)f2b(acc[1]) << 16);
    o.y = (uint)f2b(acc[2]) | ((uint)f2b(acc[3]) << 16);
    o.z = (uint)f2b(acc[4]) | ((uint)f2b(acc[5]) << 16);
    o.w = (uint)f2b(acc[6]) | ((uint)f2b(acc[7]) << 16);
    ((uint4*)dst)[(size_t)node * 16 + c] = o;
}

// ---------------- MFMA GEMM: out = A1@W1.T (+ A2@W2.T) (+bias) (relu), bf16 ----------
__global__ __launch_bounds__(256) void gc_gemm_mfma(const ushort* __restrict__ A1,
                                                    const ushort* __restrict__ W1,
                                                    const ushort* __restrict__ A2,
                                                    const ushort* __restrict__ W2,
                                                    const float* __restrict__ bias,
                                                    ushort* __restrict__ out,
                                                    int nrows, int do_relu) {
    __shared__ ushort lds[128 * 136];  // 34816 B; epilogue reuses first 17408 B
    const int t = threadIdx.x;
    const int w = t >> 6;
    const int l = t & 63;
    const int lr = l & 15;   // A row in tile / B col in tile
    const int g = l >> 4;    // k-group
    const int row0 = blockIdx.x * 64 + w * 16;

    f32x4 acc[8];
#pragma unroll
    for (int i = 0; i < 8; ++i) acc[i] = (f32x4){0.f, 0.f, 0.f, 0.f};

    const int nmat = (A2 != nullptr) ? 2 : 1;
    for (int mat = 0; mat < nmat; ++mat) {
        const ushort* __restrict__ A = mat ? A2 : A1;
        const ushort* __restrict__ W = mat ? W2 : W1;
        __syncthreads();
        // stage W: 128 rows x 16 chunks of 16B = 2048 chunks
#pragma unroll
        for (int i = 0; i < 8; ++i) {
            int cid = i * 256 + t;
            int r = cid >> 4, ch = cid & 15;
            *(uint4*)(&lds[r * 136 + ch * 8]) = ((const uint4*)W)[cid];
        }
        __syncthreads();

        short8 af[4];
        const int arow = row0 + lr;
        const bool ok = arow < nrows;
#pragma unroll
        for (int ks = 0; ks < 4; ++ks) {
            if (ok)
                af[ks] = *(const short8*)(A + (size_t)arow * 128 + ks * 32 + g * 8);
            else
                af[ks] = (short8){0, 0, 0, 0, 0, 0, 0, 0};
        }
#pragma unroll
        for (int ct = 0; ct < 8; ++ct) {
#pragma unroll
            for (int ks = 0; ks < 4; ++ks) {
                short8 bf = *(const short8*)(&lds[(ct * 16 + lr) * 136 + ks * 32 + g * 8]);
                acc[ct] = __builtin_amdgcn_mfma_f32_16x16x32_bf16(af[ks], bf, acc[ct], 0, 0, 0);
            }
        }
    }

    float bv[8];
#pragma unroll
    for (int ct = 0; ct < 8; ++ct) bv[ct] = bias ? bias[ct * 16 + lr] : 0.f;

    __syncthreads();
    ushort* ep = &lds[w * (16 * 136)];
#pragma unroll
    for (int ct = 0; ct < 8; ++ct) {
#pragma unroll
        for (int r = 0; r < 4; ++r) {
            float v = acc[ct][r] + bv[ct];
            if (do_relu) v = fmaxf(v, 0.f);
            ep[(g * 4 + r) * 136 + ct * 16 + lr] = f2b(v);
        }
    }
    __syncthreads();
#pragma unroll
    for (int i = 0; i < 4; ++i) {
        int rr = i * 4 + g;
        int grow = row0 + rr;
        if (grow < nrows) {
            uint4 vv = *(uint4*)(&ep[rr * 136 + lr * 8]);
            ((uint4*)out)[(size_t)grow * 16 + lr] = vv;
        }
    }
}

// ---------------- pooling (bf16 in, fp32 accumulate; batch sorted) ----------------
__global__ __launch_bounds__(256) void gc_pool(const ushort* __restrict__ h,
                                               const int* __restrict__ batch,
                                               float* __restrict__ psum,
                                               float* __restrict__ pcnt, int n) {
    int base = blockIdx.x * 128;
    int sub = threadIdx.x >> 6;
    int fp = threadIdx.x & 63;
    int start = base + sub * 32;
    int end = min(start + 32, n);
    if (start >= end) return;
    int cur = batch[start];
    float s0 = 0.f, s1 = 0.f;
    int run = 0;
    const uint* h2 = (const uint*)h;
    for (int node = start; node < end; ++node) {
        int g = batch[node];
        if (g != cur) {
            unsafeAtomicAdd(&psum[cur * HID + fp * 2 + 0], s0);
            unsafeAtomicAdd(&psum[cur * HID + fp * 2 + 1], s1);
            if (fp == 0) unsafeAtomicAdd(&pcnt[cur], (float)run);
            s0 = s1 = 0.f; run = 0; cur = g;
        }
        uint u = h2[(size_t)node * 64 + fp];
        s0 += __uint_as_float(u << 16);
        s1 += __uint_as_float(u & 0xffff0000u);
        ++run;
    }
    unsafeAtomicAdd(&psum[cur * HID + fp * 2 + 0], s0);
    unsafeAtomicAdd(&psum[cur * HID + fp * 2 + 1], s1);
    if (fp == 0) unsafeAtomicAdd(&pcnt[cur], (float)run);
}

// ---------------- xn = normalize(psum/cnt) ----------------
__global__ __launch_bounds__(128) void gc_finalize_xn(const float* __restrict__ psum,
                                                      const float* __restrict__ pcnt,
                                                      float* __restrict__ xn) {
    int g = blockIdx.x;
    int f = threadIdx.x;
    float c = fmaxf(pcnt[g], 1.0f);
    float v = psum[g * HID + f] / c;
    float ss = v * v;
#pragma unroll
    for (int off = 32; off >= 1; off >>= 1) ss += __shfl_xor(ss, off, 64);
    __shared__ float s2[2];
    if ((threadIdx.x & 63) == 0) s2[threadIdx.x >> 6] = ss;
    __syncthreads();
    float denom = fmaxf(sqrtf(s2[0] + s2[1]), 1e-12f);
    xn[g * HID + f] = v / denom;
}

// ---------------- out = xn @ normalize(Wl).T + bl ----------------
__global__ __launch_bounds__(256) void gc_finalize_out(const float* __restrict__ xn,
                                                       const float* __restrict__ Wl,
                                                       const float* __restrict__ bl,
                                                       float* __restrict__ out,
                                                       int G, int C) {
    __shared__ float Wn[10][128];
    int wave = threadIdx.x >> 6, lane = threadIdx.x & 63;
    for (int r = wave; r < C; r += 4) {
        float v0 = Wl[r * 128 + lane * 2 + 0];
        float v1 = Wl[r * 128 + lane * 2 + 1];
        float ss = v0 * v0 + v1 * v1;
#pragma unroll
        for (int off = 32; off >= 1; off >>= 1) ss += __shfl_xor(ss, off, 64);
        float denom = fmaxf(sqrtf(ss), 1e-12f);
        Wn[r][lane * 2 + 0] = v0 / denom;
        Wn[r][lane * 2 + 1] = v1 / denom;
    }
    __syncthreads();
    for (int idx = threadIdx.x; idx < G * C; idx += 256) {
        int g = idx / C, c = idx % C;
        const float* xr = xn + g * HID;
        float acc = bl[c];
        for (int k = 0; k < HID; ++k) acc += xr[k] * Wn[c][k];
        out[idx] = acc;
    }
}

extern "C" void kernel_launch(void* const* d_in, const int* in_sizes, int n_in,
                              void* d_out, int out_size, void* d_ws, size_t ws_size,
                              hipStream_t stream) {
    const float* x      = (const float*)d_in[0];
    const int*   ei     = (const int*)d_in[1];
    const int*   batch  = (const int*)d_in[2];
    const float* W1_rel = (const float*)d_in[3];
    const float* b1     = (const float*)d_in[4];
    const float* W1_root= (const float*)d_in[5];
    const float* W2     = (const float*)d_in[6];
    const float* b2     = (const float*)d_in[7];
    const float* W3     = (const float*)d_in[8];
    const float* b3     = (const float*)d_in[9];
    const float* Wl     = (const float*)d_in[10];
    const float* bl     = (const float*)d_in[11];

    const int N = in_sizes[0] / HID;     // 50000
    const int E = in_sizes[1] / 2;       // 800000
    const int C = 10;
    const int G = out_size / (HID + C);  // 128

    const int* row = ei;
    const int* col = ei + E;

    // workspace layout (16B alignment maintained)
    ushort* xb  = (ushort*)d_ws;                      // N*128 bf16
    ushort* hb0 = xb  + (size_t)N * HID;              // N*128 bf16
    ushort* hb1 = hb0 + (size_t)N * HID;              // N*128 bf16
    ushort* wb  = hb1 + (size_t)N * HID;              // 4*16384 bf16 weights
    float* dinv = (float*)(wb + 4 * 16384);           // N
    float* psum = dinv + N;                           // G*128
    float* pcnt = psum + (size_t)G * HID;             // G
    int*   degi = (int*)(pcnt + G);                   // N
    int*   offs = degi + N;                           // N+1
    int*   curs = offs + N + 1;                       // N
    int*   eid  = curs + N;                           // E
    int*   bsum = eid + E;                            // ceil(N/256)

    float* xn   = (float*)d_out;
    float* outp = xn + (size_t)G * HID;

    const int eb256 = (E + 255) / 256;
    const int nb256 = (N + 255) / 256;  // also the scan block count (<=256 req.)
    const int gthb  = (N * 16 + 255) / 256;   // gather: 16 lanes/node
    const int gmb   = (N + 63) / 64;          // gemm: 64 rows/block

    // ---- CSR build + dinv ----
    hipMemsetAsync(degi, 0, (size_t)N * sizeof(int), stream);
    hipMemsetAsync(psum, 0, (size_t)(G * HID + G) * sizeof(float), stream);
    gc_deg_count<<<eb256, 256, 0, stream>>>(col, degi, E);
    gc_scan_part<<<nb256, 256, 0, stream>>>(degi, bsum, N);
    gc_scan_top<<<1, 256, 0, stream>>>(bsum, nb256);
    gc_scan_final<<<nb256, 256, 0, stream>>>(degi, bsum, offs, curs, N);
    gc_fill<<<eb256, 256, 0, stream>>>(row, col, curs, eid, E);
    gc_dinv<<<nb256, 256, 0, stream>>>(degi, dinv, N);

    // ---- conversions ----
    gc_cvt<<<(N * HID / 8 + 255) / 256, 256, 0, stream>>>(x, xb, N * HID / 8);
    gc_cvt<<<8, 256, 0, stream>>>(W1_rel,  wb,             2048);
    gc_cvt<<<8, 256, 0, stream>>>(W1_root, wb + 16384,     2048);
    gc_cvt<<<8, 256, 0, stream>>>(W2,      wb + 2 * 16384, 2048);
    gc_cvt<<<8, 256, 0, stream>>>(W3,      wb + 3 * 16384, 2048);

    // conv1: agg = gather(x); h1 = relu(agg@W1_rel.T + x@W1_root.T + b1)
    gc_gather_b<<<gthb, 256, 0, stream>>>(offs, eid, xb, nullptr, nullptr, nullptr, hb0, N, 0);
    gc_gemm_mfma<<<gmb, 256, 0, stream>>>(hb0, wb, xb, wb + 16384, b1, hb1, N, 1);

    // conv2: hp2 = h1@W2.T; h2 = relu(gatherN(hp2) + hp2*dinv^2 + b2)
    gc_gemm_mfma<<<gmb, 256, 0, stream>>>(hb1, wb + 2 * 16384, nullptr, nullptr, nullptr, hb0, N, 0);
    gc_gather_b<<<gthb, 256, 0, stream>>>(offs, eid, hb0, dinv, hb0, b2, hb1, N, 1);

    // conv3: hp3 = h2@W3.T; h3 = gatherN(hp3) + hp3*dinv^2 + b3
    gc_gemm_mfma<<<gmb, 256, 0, stream>>>(hb1, wb + 3 * 16384, nullptr, nullptr, nullptr, hb0, N, 0);
    gc_gather_b<<<gthb, 256, 0, stream>>>(offs, eid, hb0, dinv, hb0, b3, hb1, N, 0);

    // pool + head
    gc_pool<<<(N + 127) / 128, 256, 0, stream>>>(hb1, batch, psum, pcnt, N);
    gc_finalize_xn<<<G, 128, 0, stream>>>(psum, pcnt, xn);
    gc_finalize_out<<<1, 256, 0, stream>>>(xn, Wl, bl, outp, G, C);
}

// Round 6
// 363.871 us; speedup vs baseline: 12.4923x; 1.0459x over previous
//
#include <hip/hip_runtime.h>

#define HID 128

typedef __attribute__((ext_vector_type(8))) short short8;
typedef __attribute__((ext_vector_type(4))) float f32x4;

__device__ inline ushort f2b(float f) {
    union { float f; uint u; } v; v.f = f;
    uint u = v.u;
    return (ushort)((u + 0x7fffu + ((u >> 16) & 1u)) >> 16);  // RNE
}

__device__ inline void fma8(float* acc, uint4 u, float s) {
    acc[0] += __uint_as_float(u.x << 16) * s;
    acc[1] += __uint_as_float(u.x & 0xffff0000u) * s;
    acc[2] += __uint_as_float(u.y << 16) * s;
    acc[3] += __uint_as_float(u.y & 0xffff0000u) * s;
    acc[4] += __uint_as_float(u.z << 16) * s;
    acc[5] += __uint_as_float(u.z & 0xffff0000u) * s;
    acc[6] += __uint_as_float(u.w << 16) * s;
    acc[7] += __uint_as_float(u.w & 0xffff0000u) * s;
}

// ---------------- CSR build ----------------
__global__ __launch_bounds__(256) void gc_deg_count(const int* __restrict__ col,
                                                    int* __restrict__ deg, int E) {
    int e = blockIdx.x * 256 + threadIdx.x;
    if (e < E) atomicAdd(&deg[col[e]], 1);
}

// ---- multi-block exclusive scan: part-sums -> top scan -> final (+dinv fused) ----
__global__ __launch_bounds__(256) void gc_scan_part(const int* __restrict__ deg,
                                                    int* __restrict__ bsum, int n) {
    __shared__ int s[4];
    int i = blockIdx.x * 256 + threadIdx.x;
    int v = (i < n) ? deg[i] : 0;
#pragma unroll
    for (int off = 32; off >= 1; off >>= 1) v += __shfl_xor(v, off, 64);
    if ((threadIdx.x & 63) == 0) s[threadIdx.x >> 6] = v;
    __syncthreads();
    if (threadIdx.x == 0) bsum[blockIdx.x] = s[0] + s[1] + s[2] + s[3];
}

__global__ __launch_bounds__(256) void gc_scan_top(int* __restrict__ bsum, int B) {
    __shared__ int s[256];
    int t = threadIdx.x;
    int v = (t < B) ? bsum[t] : 0;
    s[t] = v;
    __syncthreads();
    for (int off = 1; off < 256; off <<= 1) {
        int u = (t >= off) ? s[t - off] : 0;
        __syncthreads();
        s[t] += u;
        __syncthreads();
    }
    int excl = (t == 0) ? 0 : s[t - 1];
    if (t < B) bsum[t] = excl;
}

__global__ __launch_bounds__(256) void gc_scan_final(const int* __restrict__ deg,
                                                     const int* __restrict__ bsum,
                                                     int* __restrict__ offs,
                                                     int* __restrict__ curs,
                                                     float* __restrict__ dinv, int n) {
    __shared__ int s[256];
    int t = threadIdx.x;
    int i = blockIdx.x * 256 + t;
    int v = (i < n) ? deg[i] : 0;
    s[t] = v;
    __syncthreads();
    for (int off = 1; off < 256; off <<= 1) {
        int u = (t >= off) ? s[t - off] : 0;
        __syncthreads();
        s[t] += u;
        __syncthreads();
    }
    int excl = ((t == 0) ? 0 : s[t - 1]) + bsum[blockIdx.x];
    if (i < n) {
        offs[i] = excl;
        curs[i] = excl;
        dinv[i] = rsqrtf((float)v + 1.0f);  // +1 self-loop
        if (i == n - 1) offs[n] = excl + v;
    }
}

// ---- cache-blocked bucket fill: blockIdx.y = destination partition (col>>13) ----
// Blocks dispatch in ascending ID, so each partition's random eid scatters land in
// a ~450KB L2-resident window -> each line written back ~once (locality heuristic
// only; correctness is dispatch-order independent).
__global__ __launch_bounds__(256) void gc_fill_part(const int* __restrict__ row,
                                                    const int* __restrict__ col,
                                                    int* __restrict__ cursor,
                                                    int* __restrict__ eid, int E) {
    int e = blockIdx.x * 256 + threadIdx.x;
    if (e >= E) return;
    int c = col[e];
    if ((c >> 13) != (int)blockIdx.y) return;
    int pos = atomicAdd(&cursor[c], 1);
    eid[pos] = row[e];
}

// ---------------- fp32 -> bf16 conversion (8 elems/thread) ----------------
__global__ __launch_bounds__(256) void gc_cvt(const float* __restrict__ src,
                                              ushort* __restrict__ dst, int n8) {
    int i = blockIdx.x * 256 + threadIdx.x;
    if (i >= n8) return;
    const float4* s4 = (const float4*)src;
    float4 a = s4[i * 2], b = s4[i * 2 + 1];
    uint4 o;
    o.x = (uint)f2b(a.x) | ((uint)f2b(a.y) << 16);
    o.y = (uint)f2b(a.z) | ((uint)f2b(a.w) << 16);
    o.z = (uint)f2b(b.x) | ((uint)f2b(b.y) << 16);
    o.w = (uint)f2b(b.z) | ((uint)f2b(b.w) << 16);
    ((uint4*)dst)[i] = o;
}

// all four 128x128 weights in one launch: 8192 threads, seg = i>>11
__global__ __launch_bounds__(256) void gc_cvt_w(const float* __restrict__ Wa,
                                                const float* __restrict__ Wb,
                                                const float* __restrict__ Wc,
                                                const float* __restrict__ Wd,
                                                ushort* __restrict__ dst) {
    int i = blockIdx.x * 256 + threadIdx.x;  // 0..8191
    int seg = i >> 11;
    int off = i & 2047;
    const float* src = (seg == 0) ? Wa : (seg == 1) ? Wb : (seg == 2) ? Wc : Wd;
    const float4* s4 = (const float4*)src;
    float4 a = s4[off * 2], b = s4[off * 2 + 1];
    uint4 o;
    o.x = (uint)f2b(a.x) | ((uint)f2b(a.y) << 16);
    o.y = (uint)f2b(a.z) | ((uint)f2b(a.w) << 16);
    o.z = (uint)f2b(b.x) | ((uint)f2b(b.y) << 16);
    o.w = (uint)f2b(b.z) | ((uint)f2b(b.w) << 16);
    ((uint4*)(dst + (size_t)seg * 16384))[off] = o;
}

// ---------------- gather (bf16 in/out, fp32 accumulate), unroll-4 ----------------
// 16 lanes per node, 16B (8 bf16) per lane.
__global__ __launch_bounds__(256) void gc_gather_b(const int* __restrict__ offs,
                                                   const int* __restrict__ eid,
                                                   const ushort* __restrict__ src,
                                                   const float* __restrict__ dinv,
                                                   const ushort* __restrict__ selfh,
                                                   const float* __restrict__ bias,
                                                   ushort* __restrict__ dst,
                                                   int n, int do_relu) {
    int node = (blockIdx.x * 256 + threadIdx.x) >> 4;
    if (node >= n) return;
    const int c = threadIdx.x & 15;
    const int s = offs[node], e = offs[node + 1];
    const bool un = (dinv != nullptr);
    const float dd = un ? dinv[node] : 1.0f;
    const uint4* __restrict__ src4 = (const uint4*)src;  // 16 uint4 per row

    float acc[8];
#pragma unroll
    for (int k = 0; k < 8; ++k) acc[k] = 0.f;

    int j = s;
    for (; j + 3 < e; j += 4) {
        int r0 = eid[j], r1 = eid[j + 1], r2 = eid[j + 2], r3 = eid[j + 3];
        float s0 = un ? dinv[r0] * dd : 1.0f;
        float s1 = un ? dinv[r1] * dd : 1.0f;
        float s2 = un ? dinv[r2] * dd : 1.0f;
        float s3 = un ? dinv[r3] * dd : 1.0f;
        uint4 u0 = src4[(size_t)r0 * 16 + c];
        uint4 u1 = src4[(size_t)r1 * 16 + c];
        uint4 u2 = src4[(size_t)r2 * 16 + c];
        uint4 u3 = src4[(size_t)r3 * 16 + c];
        fma8(acc, u0, s0);
        fma8(acc, u1, s1);
        fma8(acc, u2, s2);
        fma8(acc, u3, s3);
    }
    for (; j < e; ++j) {
        int r0 = eid[j];
        float s0 = un ? dinv[r0] * dd : 1.0f;
        fma8(acc, src4[(size_t)r0 * 16 + c], s0);
    }
    if (selfh) {
        float di2 = dd * dd;
        fma8(acc, ((const uint4*)selfh)[(size_t)node * 16 + c], di2);
#pragma unroll
        for (int k = 0; k < 8; ++k) acc[k] += bias[c * 8 + k];
    }
    if (do_relu) {
#pragma unroll
        for (int k = 0; k < 8; ++k) acc[k] = fmaxf(acc[k], 0.f);
    }
    uint4 o;
    o.x = (uint)f2b(acc[0]) | ((uint)f2b(acc[1]) << 16);
    o.y = (uint)f2b(acc[2]) | ((uint)f2b(acc[3]) << 16);
    o.z = (uint)f2b(acc[4]) | ((uint)f2b(acc[5]) << 16);
    o.w = (uint)f2b(acc[6]) | ((uint)f2b(acc[7]) << 16);
    ((uint4*)dst)[(size_t)node * 16 + c] = o;
}

// ---------------- MFMA GEMM: out = A1@W1.T (+ A2@W2.T) (+bias) (relu), bf16 ----------
__global__ __launch_bounds__(256) void gc_gemm_mfma(const ushort* __restrict__ A1,
                                                    const ushort* __restrict__ W1,
                                                    const ushort* __restrict__ A2,
                                                    const ushort* __restrict__ W2,
                                                    const float* __restrict__ bias,
                                                    ushort* __restrict__ out,
                                                    int nrows, int do_relu) {
    __shared__ ushort lds[128 * 136];  // 34816 B; epilogue reuses first 17408 B
    const int t = threadIdx.x;
    const int w = t >> 6;
    const int l = t & 63;
    const int lr = l & 15;   // A row in tile / B col in tile
    const int g = l >> 4;    // k-group
    const int row0 = blockIdx.x * 64 + w * 16;

    f32x4 acc[8];
#pragma unroll
    for (int i = 0; i < 8; ++i) acc[i] = (f32x4){0.f, 0.f, 0.f, 0.f};

    const int nmat = (A2 != nullptr) ? 2 : 1;
    for (int mat = 0; mat < nmat; ++mat) {
        const ushort* __restrict__ A = mat ? A2 : A1;
        const ushort* __restrict__ W = mat ? W2 : W1;
        __syncthreads();
        // stage W: 128 rows x 16 chunks of 16B = 2048 chunks
#pragma unroll
        for (int i = 0; i < 8; ++i) {
            int cid = i * 256 + t;
            int r = cid >> 4, ch = cid & 15;
            *(uint4*)(&lds[r * 136 + ch * 8]) = ((const uint4*)W)[cid];
        }
        __syncthreads();

        short8 af[4];
        const int arow = row0 + lr;
        const bool ok = arow < nrows;
#pragma unroll
        for (int ks = 0; ks < 4; ++ks) {
            if (ok)
                af[ks] = *(const short8*)(A + (size_t)arow * 128 + ks * 32 + g * 8);
            else
                af[ks] = (short8){0, 0, 0, 0, 0, 0, 0, 0};
        }
#pragma unroll
        for (int ct = 0; ct < 8; ++ct) {
#pragma unroll
            for (int ks = 0; ks < 4; ++ks) {
                short8 bf = *(const short8*)(&lds[(ct * 16 + lr) * 136 + ks * 32 + g * 8]);
                acc[ct] = __builtin_amdgcn_mfma_f32_16x16x32_bf16(af[ks], bf, acc[ct], 0, 0, 0);
            }
        }
    }

    float bv[8];
#pragma unroll
    for (int ct = 0; ct < 8; ++ct) bv[ct] = bias ? bias[ct * 16 + lr] : 0.f;

    __syncthreads();
    ushort* ep = &lds[w * (16 * 136)];
#pragma unroll
    for (int ct = 0; ct < 8; ++ct) {
#pragma unroll
        for (int r = 0; r < 4; ++r) {
            float v = acc[ct][r] + bv[ct];
            if (do_relu) v = fmaxf(v, 0.f);
            ep[(g * 4 + r) * 136 + ct * 16 + lr] = f2b(v);
        }
    }
    __syncthreads();
#pragma unroll
    for (int i = 0; i < 4; ++i) {
        int rr = i * 4 + g;
        int grow = row0 + rr;
        if (grow < nrows) {
            uint4 vv = *(uint4*)(&ep[rr * 136 + lr * 8]);
            ((uint4*)out)[(size_t)grow * 16 + lr] = vv;
        }
    }
}

// ---------------- pooling (bf16 in, fp32 accumulate; batch sorted) ----------------
__global__ __launch_bounds__(256) void gc_pool(const ushort* __restrict__ h,
                                               const int* __restrict__ batch,
                                               float* __restrict__ psum,
                                               float* __restrict__ pcnt, int n) {
    int base = blockIdx.x * 128;
    int sub = threadIdx.x >> 6;
    int fp = threadIdx.x & 63;
    int start = base + sub * 32;
    int end = min(start + 32, n);
    if (start >= end) return;
    int cur = batch[start];
    float s0 = 0.f, s1 = 0.f;
    int run = 0;
    const uint* h2 = (const uint*)h;
    for (int node = start; node < end; ++node) {
        int g = batch[node];
        if (g != cur) {
            unsafeAtomicAdd(&psum[cur * HID + fp * 2 + 0], s0);
            unsafeAtomicAdd(&psum[cur * HID + fp * 2 + 1], s1);
            if (fp == 0) unsafeAtomicAdd(&pcnt[cur], (float)run);
            s0 = s1 = 0.f; run = 0; cur = g;
        }
        uint u = h2[(size_t)node * 64 + fp];
        s0 += __uint_as_float(u << 16);
        s1 += __uint_as_float(u & 0xffff0000u);
        ++run;
    }
    unsafeAtomicAdd(&psum[cur * HID + fp * 2 + 0], s0);
    unsafeAtomicAdd(&psum[cur * HID + fp * 2 + 1], s1);
    if (fp == 0) unsafeAtomicAdd(&pcnt[cur], (float)run);
}

// ---------------- xn = normalize(psum/cnt) ----------------
__global__ __launch_bounds__(128) void gc_finalize_xn(const float* __restrict__ psum,
                                                      const float* __restrict__ pcnt,
                                                      float* __restrict__ xn) {
    int g = blockIdx.x;
    int f = threadIdx.x;
    float c = fmaxf(pcnt[g], 1.0f);
    float v = psum[g * HID + f] / c;
    float ss = v * v;
#pragma unroll
    for (int off = 32; off >= 1; off >>= 1) ss += __shfl_xor(ss, off, 64);
    __shared__ float s2[2];
    if ((threadIdx.x & 63) == 0) s2[threadIdx.x >> 6] = ss;
    __syncthreads();
    float denom = fmaxf(sqrtf(s2[0] + s2[1]), 1e-12f);
    xn[g * HID + f] = v / denom;
}

// ---------------- out = xn @ normalize(Wl).T + bl ----------------
__global__ __launch_bounds__(256) void gc_finalize_out(const float* __restrict__ xn,
                                                       const float* __restrict__ Wl,
                                                       const float* __restrict__ bl,
                                                       float* __restrict__ out,
                                                       int G, int C) {
    __shared__ float Wn[10][128];
    int wave = threadIdx.x >> 6, lane = threadIdx.x & 63;
    for (int r = wave; r < C; r += 4) {
        float v0 = Wl[r * 128 + lane * 2 + 0];
        float v1 = Wl[r * 128 + lane * 2 + 1];
        float ss = v0 * v0 + v1 * v1;
#pragma unroll
        for (int off = 32; off >= 1; off >>= 1) ss += __shfl_xor(ss, off, 64);
        float denom = fmaxf(sqrtf(ss), 1e-12f);
        Wn[r][lane * 2 + 0] = v0 / denom;
        Wn[r][lane * 2 + 1] = v1 / denom;
    }
    __syncthreads();
    for (int idx = threadIdx.x; idx < G * C; idx += 256) {
        int g = idx / C, c = idx % C;
        const float* xr = xn + g * HID;
        float acc = bl[c];
        for (int k = 0; k < HID; ++k) acc += xr[k] * Wn[c][k];
        out[idx] = acc;
    }
}

extern "C" void kernel_launch(void* const* d_in, const int* in_sizes, int n_in,
                              void* d_out, int out_size, void* d_ws, size_t ws_size,
                              hipStream_t stream) {
    const float* x      = (const float*)d_in[0];
    const int*   ei     = (const int*)d_in[1];
    const int*   batch  = (const int*)d_in[2];
    const float* W1_rel = (const float*)d_in[3];
    const float* b1     = (const float*)d_in[4];
    const float* W1_root= (const float*)d_in[5];
    const float* W2     = (const float*)d_in[6];
    const float* b2     = (const float*)d_in[7];
    const float* W3     = (const float*)d_in[8];
    const float* b3     = (const float*)d_in[9];
    const float* Wl     = (const float*)d_in[10];
    const float* bl     = (const float*)d_in[11];

    const int N = in_sizes[0] / HID;     // 50000
    const int E = in_sizes[1] / 2;       // 800000
    const int C = 10;
    const int G = out_size / (HID + C);  // 128

    const int* row = ei;
    const int* col = ei + E;

    // workspace layout (16B alignment maintained)
    ushort* xb  = (ushort*)d_ws;                      // N*128 bf16
    ushort* hb0 = xb  + (size_t)N * HID;              // N*128 bf16
    ushort* hb1 = hb0 + (size_t)N * HID;              // N*128 bf16
    ushort* wb  = hb1 + (size_t)N * HID;              // 4*16384 bf16 weights
    float* dinv = (float*)(wb + 4 * 16384);           // N
    float* psum = dinv + N;                           // G*128
    float* pcnt = psum + (size_t)G * HID;             // G
    int*   degi = (int*)(pcnt + G);                   // N
    int*   offs = degi + N;                           // N+1
    int*   curs = offs + N + 1;                       // N
    int*   eid  = curs + N;                           // E
    int*   bsum = eid + E;                            // ceil(N/256)

    float* xn   = (float*)d_out;
    float* outp = xn + (size_t)G * HID;

    const int eb256 = (E + 255) / 256;
    const int nb256 = (N + 255) / 256;        // scan block count (<=256 required)
    const int gthb  = (N * 16 + 255) / 256;   // gather: 16 lanes/node
    const int gmb   = (N + 63) / 64;          // gemm: 64 rows/block
    const int nparts = ((N - 1) >> 13) + 1;   // fill partitions (col>>13)

    // ---- CSR build + dinv ----
    hipMemsetAsync(degi, 0, (size_t)N * sizeof(int), stream);
    hipMemsetAsync(psum, 0, (size_t)(G * HID + G) * sizeof(float), stream);
    gc_deg_count<<<eb256, 256, 0, stream>>>(col, degi, E);
    gc_scan_part<<<nb256, 256, 0, stream>>>(degi, bsum, N);
    gc_scan_top<<<1, 256, 0, stream>>>(bsum, nb256);
    gc_scan_final<<<nb256, 256, 0, stream>>>(degi, bsum, offs, curs, dinv, N);
    gc_fill_part<<<dim3(eb256, nparts), 256, 0, stream>>>(row, col, curs, eid, E);

    // ---- conversions ----
    gc_cvt<<<(N * HID / 8 + 255) / 256, 256, 0, stream>>>(x, xb, N * HID / 8);
    gc_cvt_w<<<32, 256, 0, stream>>>(W1_rel, W1_root, W2, W3, wb);

    // conv1: agg = gather(x); h1 = relu(agg@W1_rel.T + x@W1_root.T + b1)
    gc_gather_b<<<gthb, 256, 0, stream>>>(offs, eid, xb, nullptr, nullptr, nullptr, hb0, N, 0);
    gc_gemm_mfma<<<gmb, 256, 0, stream>>>(hb0, wb, xb, wb + 16384, b1, hb1, N, 1);

    // conv2: hp2 = h1@W2.T; h2 = relu(gatherN(hp2) + hp2*dinv^2 + b2)
    gc_gemm_mfma<<<gmb, 256, 0, stream>>>(hb1, wb + 2 * 16384, nullptr, nullptr, nullptr, hb0, N, 0);
    gc_gather_b<<<gthb, 256, 0, stream>>>(offs, eid, hb0, dinv, hb0, b2, hb1, N, 1);

    // conv3: hp3 = h2@W3.T; h3 = gatherN(hp3) + hp3*dinv^2 + b3
    gc_gemm_mfma<<<gmb, 256, 0, stream>>>(hb1, wb + 3 * 16384, nullptr, nullptr, nullptr, hb0, N, 0);
    gc_gather_b<<<gthb, 256, 0, stream>>>(offs, eid, hb0, dinv, hb0, b3, hb1, N, 0);

    // pool + head
    gc_pool<<<(N + 127) / 128, 256, 0, stream>>>(hb1, batch, psum, pcnt, N);
    gc_finalize_xn<<<G, 128, 0, stream>>>(psum, pcnt, xn);
    gc_finalize_out<<<1, 256, 0, stream>>>(xn, Wl, bl, outp, G, C);
}

// Round 7
// 354.539 us; speedup vs baseline: 12.8211x; 1.0263x over previous
//
#include <hip/hip_runtime.h>

#define HID 128

typedef __attribute__((ext_vector_type(8))) short short8;
typedef __attribute__((ext_vector_type(4))) float f32x4;

__device__ inline ushort f2b(float f) {
    union { float f; uint u; } v; v.f = f;
    uint u = v.u;
    return (ushort)((u + 0x7fffu + ((u >> 16) & 1u)) >> 16);  // RNE
}

__device__ inline void fma8(float* acc, uint4 u, float s) {
    acc[0] += __uint_as_float(u.x << 16) * s;
    acc[1] += __uint_as_float(u.x & 0xffff0000u) * s;
    acc[2] += __uint_as_float(u.y << 16) * s;
    acc[3] += __uint_as_float(u.y & 0xffff0000u) * s;
    acc[4] += __uint_as_float(u.z << 16) * s;
    acc[5] += __uint_as_float(u.z & 0xffff0000u) * s;
    acc[6] += __uint_as_float(u.w << 16) * s;
    acc[7] += __uint_as_float(u.w & 0xffff0000u) * s;
}

// ---------------- CSR build ----------------
__global__ __launch_bounds__(256) void gc_deg_count(const int* __restrict__ col,
                                                    int* __restrict__ deg, int E) {
    int e = blockIdx.x * 256 + threadIdx.x;
    if (e < E) atomicAdd(&deg[col[e]], 1);
}

// ---- multi-block exclusive scan: part-sums -> top scan -> final (+dinv fused) ----
__global__ __launch_bounds__(256) void gc_scan_part(const int* __restrict__ deg,
                                                    int* __restrict__ bsum, int n) {
    __shared__ int s[4];
    int i = blockIdx.x * 256 + threadIdx.x;
    int v = (i < n) ? deg[i] : 0;
#pragma unroll
    for (int off = 32; off >= 1; off >>= 1) v += __shfl_xor(v, off, 64);
    if ((threadIdx.x & 63) == 0) s[threadIdx.x >> 6] = v;
    __syncthreads();
    if (threadIdx.x == 0) bsum[blockIdx.x] = s[0] + s[1] + s[2] + s[3];
}

__global__ __launch_bounds__(256) void gc_scan_top(int* __restrict__ bsum, int B) {
    __shared__ int s[256];
    int t = threadIdx.x;
    int v = (t < B) ? bsum[t] : 0;
    s[t] = v;
    __syncthreads();
    for (int off = 1; off < 256; off <<= 1) {
        int u = (t >= off) ? s[t - off] : 0;
        __syncthreads();
        s[t] += u;
        __syncthreads();
    }
    int excl = (t == 0) ? 0 : s[t - 1];
    if (t < B) bsum[t] = excl;
}

__global__ __launch_bounds__(256) void gc_scan_final(const int* __restrict__ deg,
                                                     const int* __restrict__ bsum,
                                                     int* __restrict__ offs,
                                                     int* __restrict__ curs,
                                                     float* __restrict__ dinv, int n) {
    __shared__ int s[256];
    int t = threadIdx.x;
    int i = blockIdx.x * 256 + t;
    int v = (i < n) ? deg[i] : 0;
    s[t] = v;
    __syncthreads();
    for (int off = 1; off < 256; off <<= 1) {
        int u = (t >= off) ? s[t - off] : 0;
        __syncthreads();
        s[t] += u;
        __syncthreads();
    }
    int excl = ((t == 0) ? 0 : s[t - 1]) + bsum[blockIdx.x];
    if (i < n) {
        offs[i] = excl;
        curs[i] = excl;
        dinv[i] = rsqrtf((float)v + 1.0f);  // +1 self-loop
        if (i == n - 1) offs[n] = excl + v;
    }
}

// ---- XCD-pinned bucket fill ----
// block b: edge chunk b>>3, partition p = b&7 (node range ~N/8). With the CDNA
// round-robin XCD assignment (XCD = blockID % 8), every eid cache line is written
// by exactly one XCD's L2 -> written back once. Heuristic only; correctness is
// placement-independent (each edge claimed by exactly one block).
__global__ __launch_bounds__(256) void gc_fill_xcd(const int* __restrict__ row,
                                                   const int* __restrict__ col,
                                                   int* __restrict__ cursor,
                                                   int* __restrict__ eid,
                                                   int E, float pscale) {
    const int part = blockIdx.x & 7;
    int e = (blockIdx.x >> 3) * 256 + threadIdx.x;
    if (e >= E) return;
    int c = col[e];
    int p = min(7, (int)((float)c * pscale));
    if (p != part) return;
    int pos = atomicAdd(&cursor[c], 1);
    eid[pos] = row[e];
}

// ---------------- fp32 -> bf16 conversion (8 elems/thread) ----------------
__global__ __launch_bounds__(256) void gc_cvt(const float* __restrict__ src,
                                              ushort* __restrict__ dst, int n8) {
    int i = blockIdx.x * 256 + threadIdx.x;
    if (i >= n8) return;
    const float4* s4 = (const float4*)src;
    float4 a = s4[i * 2], b = s4[i * 2 + 1];
    uint4 o;
    o.x = (uint)f2b(a.x) | ((uint)f2b(a.y) << 16);
    o.y = (uint)f2b(a.z) | ((uint)f2b(a.w) << 16);
    o.z = (uint)f2b(b.x) | ((uint)f2b(b.y) << 16);
    o.w = (uint)f2b(b.z) | ((uint)f2b(b.w) << 16);
    ((uint4*)dst)[i] = o;
}

// all four 128x128 weights in one launch: 8192 threads, seg = i>>11
__global__ __launch_bounds__(256) void gc_cvt_w(const float* __restrict__ Wa,
                                                const float* __restrict__ Wb,
                                                const float* __restrict__ Wc,
                                                const float* __restrict__ Wd,
                                                ushort* __restrict__ dst) {
    int i = blockIdx.x * 256 + threadIdx.x;  // 0..8191
    int seg = i >> 11;
    int off = i & 2047;
    const float* src = (seg == 0) ? Wa : (seg == 1) ? Wb : (seg == 2) ? Wc : Wd;
    const float4* s4 = (const float4*)src;
    float4 a = s4[off * 2], b = s4[off * 2 + 1];
    uint4 o;
    o.x = (uint)f2b(a.x) | ((uint)f2b(a.y) << 16);
    o.y = (uint)f2b(a.z) | ((uint)f2b(a.w) << 16);
    o.z = (uint)f2b(b.x) | ((uint)f2b(b.y) << 16);
    o.w = (uint)f2b(b.z) | ((uint)f2b(b.w) << 16);
    ((uint4*)(dst + (size_t)seg * 16384))[off] = o;
}

// ---------------- gather (bf16 in/out, fp32 accumulate), unroll-4 ----------------
// 16 lanes per node, 16B (8 bf16) per lane.
__global__ __launch_bounds__(256) void gc_gather_b(const int* __restrict__ offs,
                                                   const int* __restrict__ eid,
                                                   const ushort* __restrict__ src,
                                                   const float* __restrict__ dinv,
                                                   const ushort* __restrict__ selfh,
                                                   const float* __restrict__ bias,
                                                   ushort* __restrict__ dst,
                                                   int n, int do_relu) {
    int node = (blockIdx.x * 256 + threadIdx.x) >> 4;
    if (node >= n) return;
    const int c = threadIdx.x & 15;
    const int s = offs[node], e = offs[node + 1];
    const bool un = (dinv != nullptr);
    const float dd = un ? dinv[node] : 1.0f;
    const uint4* __restrict__ src4 = (const uint4*)src;  // 16 uint4 per row

    float acc[8];
#pragma unroll
    for (int k = 0; k < 8; ++k) acc[k] = 0.f;

    int j = s;
    for (; j + 3 < e; j += 4) {
        int r0 = eid[j], r1 = eid[j + 1], r2 = eid[j + 2], r3 = eid[j + 3];
        float s0 = un ? dinv[r0] * dd : 1.0f;
        float s1 = un ? dinv[r1] * dd : 1.0f;
        float s2 = un ? dinv[r2] * dd : 1.0f;
        float s3 = un ? dinv[r3] * dd : 1.0f;
        uint4 u0 = src4[(size_t)r0 * 16 + c];
        uint4 u1 = src4[(size_t)r1 * 16 + c];
        uint4 u2 = src4[(size_t)r2 * 16 + c];
        uint4 u3 = src4[(size_t)r3 * 16 + c];
        fma8(acc, u0, s0);
        fma8(acc, u1, s1);
        fma8(acc, u2, s2);
        fma8(acc, u3, s3);
    }
    for (; j < e; ++j) {
        int r0 = eid[j];
        float s0 = un ? dinv[r0] * dd : 1.0f;
        fma8(acc, src4[(size_t)r0 * 16 + c], s0);
    }
    if (selfh) {
        float di2 = dd * dd;
        fma8(acc, ((const uint4*)selfh)[(size_t)node * 16 + c], di2);
#pragma unroll
        for (int k = 0; k < 8; ++k) acc[k] += bias[c * 8 + k];
    }
    if (do_relu) {
#pragma unroll
        for (int k = 0; k < 8; ++k) acc[k] = fmaxf(acc[k], 0.f);
    }
    uint4 o;
    o.x = (uint)f2b(acc[0]) | ((uint)f2b(acc[1]) << 16);
    o.y = (uint)f2b(acc[2]) | ((uint)f2b(acc[3]) << 16);
    o.z = (uint)f2b(acc[4]) | ((uint)f2b(acc[5]) << 16);
    o.w = (uint)f2b(acc[6]) | ((uint)f2b(acc[7]) << 16);
    ((uint4*)dst)[(size_t)node * 16 + c] = o;
}

// ---------------- MFMA GEMM: out = A1@W1.T (+ A2@W2.T) (+bias) (relu), bf16 ----------
__global__ __launch_bounds__(256) void gc_gemm_mfma(const ushort* __restrict__ A1,
                                                    const ushort* __restrict__ W1,
                                                    const ushort* __restrict__ A2,
                                                    const ushort* __restrict__ W2,
                                                    const float* __restrict__ bias,
                                                    ushort* __restrict__ out,
                                                    int nrows, int do_relu) {
    __shared__ ushort lds[128 * 136];  // 34816 B; epilogue reuses first 17408 B
    const int t = threadIdx.x;
    const int w = t >> 6;
    const int l = t & 63;
    const int lr = l & 15;   // A row in tile / B col in tile
    const int g = l >> 4;    // k-group
    const int row0 = blockIdx.x * 64 + w * 16;

    f32x4 acc[8];
#pragma unroll
    for (int i = 0; i < 8; ++i) acc[i] = (f32x4){0.f, 0.f, 0.f, 0.f};

    const int nmat = (A2 != nullptr) ? 2 : 1;
    for (int mat = 0; mat < nmat; ++mat) {
        const ushort* __restrict__ A = mat ? A2 : A1;
        const ushort* __restrict__ W = mat ? W2 : W1;
        __syncthreads();
        // stage W: 128 rows x 16 chunks of 16B = 2048 chunks
#pragma unroll
        for (int i = 0; i < 8; ++i) {
            int cid = i * 256 + t;
            int r = cid >> 4, ch = cid & 15;
            *(uint4*)(&lds[r * 136 + ch * 8]) = ((const uint4*)W)[cid];
        }
        __syncthreads();

        short8 af[4];
        const int arow = row0 + lr;
        const bool ok = arow < nrows;
#pragma unroll
        for (int ks = 0; ks < 4; ++ks) {
            if (ok)
                af[ks] = *(const short8*)(A + (size_t)arow * 128 + ks * 32 + g * 8);
            else
                af[ks] = (short8){0, 0, 0, 0, 0, 0, 0, 0};
        }
#pragma unroll
        for (int ct = 0; ct < 8; ++ct) {
#pragma unroll
            for (int ks = 0; ks < 4; ++ks) {
                short8 bf = *(const short8*)(&lds[(ct * 16 + lr) * 136 + ks * 32 + g * 8]);
                acc[ct] = __builtin_amdgcn_mfma_f32_16x16x32_bf16(af[ks], bf, acc[ct], 0, 0, 0);
            }
        }
    }

    float bv[8];
#pragma unroll
    for (int ct = 0; ct < 8; ++ct) bv[ct] = bias ? bias[ct * 16 + lr] : 0.f;

    __syncthreads();
    ushort* ep = &lds[w * (16 * 136)];
#pragma unroll
    for (int ct = 0; ct < 8; ++ct) {
#pragma unroll
        for (int r = 0; r < 4; ++r) {
            float v = acc[ct][r] + bv[ct];
            if (do_relu) v = fmaxf(v, 0.f);
            ep[(g * 4 + r) * 136 + ct * 16 + lr] = f2b(v);
        }
    }
    __syncthreads();
#pragma unroll
    for (int i = 0; i < 4; ++i) {
        int rr = i * 4 + g;
        int grow = row0 + rr;
        if (grow < nrows) {
            uint4 vv = *(uint4*)(&ep[rr * 136 + lr * 8]);
            ((uint4*)out)[(size_t)grow * 16 + lr] = vv;
        }
    }
}

// ---------------- pooling (bf16 in, fp32 accumulate; batch sorted) ----------------
__global__ __launch_bounds__(256) void gc_pool(const ushort* __restrict__ h,
                                               const int* __restrict__ batch,
                                               float* __restrict__ psum,
                                               float* __restrict__ pcnt, int n) {
    int base = blockIdx.x * 128;
    int sub = threadIdx.x >> 6;
    int fp = threadIdx.x & 63;
    int start = base + sub * 32;
    int end = min(start + 32, n);
    if (start >= end) return;
    int cur = batch[start];
    float s0 = 0.f, s1 = 0.f;
    int run = 0;
    const uint* h2 = (const uint*)h;
    for (int node = start; node < end; ++node) {
        int g = batch[node];
        if (g != cur) {
            unsafeAtomicAdd(&psum[cur * HID + fp * 2 + 0], s0);
            unsafeAtomicAdd(&psum[cur * HID + fp * 2 + 1], s1);
            if (fp == 0) unsafeAtomicAdd(&pcnt[cur], (float)run);
            s0 = s1 = 0.f; run = 0; cur = g;
        }
        uint u = h2[(size_t)node * 64 + fp];
        s0 += __uint_as_float(u << 16);
        s1 += __uint_as_float(u & 0xffff0000u);
        ++run;
    }
    unsafeAtomicAdd(&psum[cur * HID + fp * 2 + 0], s0);
    unsafeAtomicAdd(&psum[cur * HID + fp * 2 + 1], s1);
    if (fp == 0) unsafeAtomicAdd(&pcnt[cur], (float)run);
}

// ---------------- xn = normalize(psum/cnt) ----------------
__global__ __launch_bounds__(128) void gc_finalize_xn(const float* __restrict__ psum,
                                                      const float* __restrict__ pcnt,
                                                      float* __restrict__ xn) {
    int g = blockIdx.x;
    int f = threadIdx.x;
    float c = fmaxf(pcnt[g], 1.0f);
    float v = psum[g * HID + f] / c;
    float ss = v * v;
#pragma unroll
    for (int off = 32; off >= 1; off >>= 1) ss += __shfl_xor(ss, off, 64);
    __shared__ float s2[2];
    if ((threadIdx.x & 63) == 0) s2[threadIdx.x >> 6] = ss;
    __syncthreads();
    float denom = fmaxf(sqrtf(s2[0] + s2[1]), 1e-12f);
    xn[g * HID + f] = v / denom;
}

// ---------------- out = xn @ normalize(Wl).T + bl ----------------
__global__ __launch_bounds__(256) void gc_finalize_out(const float* __restrict__ xn,
                                                       const float* __restrict__ Wl,
                                                       const float* __restrict__ bl,
                                                       float* __restrict__ out,
                                                       int G, int C) {
    __shared__ float Wn[10][128];
    int wave = threadIdx.x >> 6, lane = threadIdx.x & 63;
    for (int r = wave; r < C; r += 4) {
        float v0 = Wl[r * 128 + lane * 2 + 0];
        float v1 = Wl[r * 128 + lane * 2 + 1];
        float ss = v0 * v0 + v1 * v1;
#pragma unroll
        for (int off = 32; off >= 1; off >>= 1) ss += __shfl_xor(ss, off, 64);
        float denom = fmaxf(sqrtf(ss), 1e-12f);
        Wn[r][lane * 2 + 0] = v0 / denom;
        Wn[r][lane * 2 + 1] = v1 / denom;
    }
    __syncthreads();
    for (int idx = threadIdx.x; idx < G * C; idx += 256) {
        int g = idx / C, c = idx % C;
        const float* xr = xn + g * HID;
        float acc = bl[c];
        for (int k = 0; k < HID; ++k) acc += xr[k] * Wn[c][k];
        out[idx] = acc;
    }
}

extern "C" void kernel_launch(void* const* d_in, const int* in_sizes, int n_in,
                              void* d_out, int out_size, void* d_ws, size_t ws_size,
                              hipStream_t stream) {
    const float* x      = (const float*)d_in[0];
    const int*   ei     = (const int*)d_in[1];
    const int*   batch  = (const int*)d_in[2];
    const float* W1_rel = (const float*)d_in[3];
    const float* b1     = (const float*)d_in[4];
    const float* W1_root= (const float*)d_in[5];
    const float* W2     = (const float*)d_in[6];
    const float* b2     = (const float*)d_in[7];
    const float* W3     = (const float*)d_in[8];
    const float* b3     = (const float*)d_in[9];
    const float* Wl     = (const float*)d_in[10];
    const float* bl     = (const float*)d_in[11];

    const int N = in_sizes[0] / HID;     // 50000
    const int E = in_sizes[1] / 2;       // 800000
    const int C = 10;
    const int G = out_size / (HID + C);  // 128

    const int* row = ei;
    const int* col = ei + E;

    // workspace layout (16B alignment maintained)
    ushort* xb  = (ushort*)d_ws;                      // N*128 bf16
    ushort* hb0 = xb  + (size_t)N * HID;              // N*128 bf16
    ushort* hb1 = hb0 + (size_t)N * HID;              // N*128 bf16
    ushort* wb  = hb1 + (size_t)N * HID;              // 4*16384 bf16 weights
    float* dinv = (float*)(wb + 4 * 16384);           // N
    float* psum = dinv + N;                           // G*128
    float* pcnt = psum + (size_t)G * HID;             // G
    int*   degi = (int*)(pcnt + G);                   // N
    int*   offs = degi + N;                           // N+1
    int*   curs = offs + N + 1;                       // N
    int*   eid  = curs + N;                           // E
    int*   bsum = eid + E;                            // ceil(N/256)

    float* xn   = (float*)d_out;
    float* outp = xn + (size_t)G * HID;

    const int eb256 = (E + 255) / 256;
    const int nb256 = (N + 255) / 256;        // scan block count (<=256 required)
    const int gthb  = (N * 16 + 255) / 256;   // gather: 16 lanes/node
    const int gmb   = (N + 63) / 64;          // gemm: 64 rows/block
    const float pscale = 8.0f / (float)N;     // node -> partition in [0,8)

    // ---- CSR build + dinv ----
    hipMemsetAsync(degi, 0, (size_t)N * sizeof(int), stream);
    hipMemsetAsync(psum, 0, (size_t)(G * HID + G) * sizeof(float), stream);
    gc_deg_count<<<eb256, 256, 0, stream>>>(col, degi, E);
    gc_scan_part<<<nb256, 256, 0, stream>>>(degi, bsum, N);
    gc_scan_top<<<1, 256, 0, stream>>>(bsum, nb256);
    gc_scan_final<<<nb256, 256, 0, stream>>>(degi, bsum, offs, curs, dinv, N);
    gc_fill_xcd<<<eb256 * 8, 256, 0, stream>>>(row, col, curs, eid, E, pscale);

    // ---- conversions ----
    gc_cvt<<<(N * HID / 8 + 255) / 256, 256, 0, stream>>>(x, xb, N * HID / 8);
    gc_cvt_w<<<32, 256, 0, stream>>>(W1_rel, W1_root, W2, W3, wb);

    // conv1: agg = gather(x); h1 = relu(agg@W1_rel.T + x@W1_root.T + b1)
    gc_gather_b<<<gthb, 256, 0, stream>>>(offs, eid, xb, nullptr, nullptr, nullptr, hb0, N, 0);
    gc_gemm_mfma<<<gmb, 256, 0, stream>>>(hb0, wb, xb, wb + 16384, b1, hb1, N, 1);

    // conv2: hp2 = h1@W2.T; h2 = relu(gatherN(hp2) + hp2*dinv^2 + b2)
    gc_gemm_mfma<<<gmb, 256, 0, stream>>>(hb1, wb + 2 * 16384, nullptr, nullptr, nullptr, hb0, N, 0);
    gc_gather_b<<<gthb, 256, 0, stream>>>(offs, eid, hb0, dinv, hb0, b2, hb1, N, 1);

    // conv3: hp3 = h2@W3.T; h3 = gatherN(hp3) + hp3*dinv^2 + b3
    gc_gemm_mfma<<<gmb, 256, 0, stream>>>(hb1, wb + 3 * 16384, nullptr, nullptr, nullptr, hb0, N, 0);
    gc_gather_b<<<gthb, 256, 0, stream>>>(offs, eid, hb0, dinv, hb0, b3, hb1, N, 0);

    // pool + head
    gc_pool<<<(N + 127) / 128, 256, 0, stream>>>(hb1, batch, psum, pcnt, N);
    gc_finalize_xn<<<G, 128, 0, stream>>>(psum, pcnt, xn);
    gc_finalize_out<<<1, 256, 0, stream>>>(xn, Wl, bl, outp, G, C);
}

// Round 8
// 339.306 us; speedup vs baseline: 13.3967x; 1.0449x over previous
//
#include <hip/hip_runtime.h>

#define HID 128

typedef __attribute__((ext_vector_type(8))) short short8;
typedef __attribute__((ext_vector_type(4))) float f32x4;

__device__ inline ushort f2b(float f) {
    union { float f; uint u; } v; v.f = f;
    uint u = v.u;
    return (ushort)((u + 0x7fffu + ((u >> 16) & 1u)) >> 16);  // RNE
}

__device__ inline void fma8(float* acc, uint4 u, float s) {
    acc[0] += __uint_as_float(u.x << 16) * s;
    acc[1] += __uint_as_float(u.x & 0xffff0000u) * s;
    acc[2] += __uint_as_float(u.y << 16) * s;
    acc[3] += __uint_as_float(u.y & 0xffff0000u) * s;
    acc[4] += __uint_as_float(u.z << 16) * s;
    acc[5] += __uint_as_float(u.z & 0xffff0000u) * s;
    acc[6] += __uint_as_float(u.w << 16) * s;
    acc[7] += __uint_as_float(u.w & 0xffff0000u) * s;
}

// ---------------- CSR build ----------------
__global__ __launch_bounds__(256) void gc_deg_count(const int* __restrict__ col,
                                                    int* __restrict__ deg, int E) {
    int e = blockIdx.x * 256 + threadIdx.x;
    if (e < E) atomicAdd(&deg[col[e]], 1);
}

// ---- multi-block exclusive scan ----
__global__ __launch_bounds__(256) void gc_scan_part(const int* __restrict__ deg,
                                                    int* __restrict__ bsum, int n) {
    __shared__ int s[4];
    int i = blockIdx.x * 256 + threadIdx.x;
    int v = (i < n) ? deg[i] : 0;
#pragma unroll
    for (int off = 32; off >= 1; off >>= 1) v += __shfl_xor(v, off, 64);
    if ((threadIdx.x & 63) == 0) s[threadIdx.x >> 6] = v;
    __syncthreads();
    if (threadIdx.x == 0) bsum[blockIdx.x] = s[0] + s[1] + s[2] + s[3];
}

__global__ __launch_bounds__(256) void gc_scan_top(int* __restrict__ bsum, int B) {
    __shared__ int s[256];
    int t = threadIdx.x;
    int v = (t < B) ? bsum[t] : 0;
    s[t] = v;
    __syncthreads();
    for (int off = 1; off < 256; off <<= 1) {
        int u = (t >= off) ? s[t - off] : 0;
        __syncthreads();
        s[t] += u;
        __syncthreads();
    }
    int excl = (t == 0) ? 0 : s[t - 1];
    if (t < B) bsum[t] = excl;
}

__global__ __launch_bounds__(256) void gc_scan_final(const int* __restrict__ deg,
                                                     const int* __restrict__ bsum,
                                                     int* __restrict__ offs,
                                                     int* __restrict__ curs,
                                                     float* __restrict__ dinv, int n) {
    __shared__ int s[256];
    int t = threadIdx.x;
    int i = blockIdx.x * 256 + t;
    int v = (i < n) ? deg[i] : 0;
    s[t] = v;
    __syncthreads();
    for (int off = 1; off < 256; off <<= 1) {
        int u = (t >= off) ? s[t - off] : 0;
        __syncthreads();
        s[t] += u;
        __syncthreads();
    }
    int excl = ((t == 0) ? 0 : s[t - 1]) + bsum[blockIdx.x];
    if (i < n) {
        offs[i] = excl;
        curs[i] = excl;
        dinv[i] = rsqrtf((float)v + 1.0f);  // +1 self-loop
        if (i == n - 1) offs[n] = excl + v;
    }
}

// ---- XCD-pinned bucket fill (ushort eid; N < 65536) ----
// block b: edge chunk b>>3, partition p = b&7 (node range ~N/8). With round-robin
// XCD assignment (XCD = blockID % 8), each eid cache line is written by exactly
// one XCD's L2 -> written back once. Heuristic; correctness placement-independent.
__global__ __launch_bounds__(256) void gc_fill_xcd(const int* __restrict__ row,
                                                   const int* __restrict__ col,
                                                   int* __restrict__ cursor,
                                                   ushort* __restrict__ eid,
                                                   int E, float pscale) {
    const int part = blockIdx.x & 7;
    int e = (blockIdx.x >> 3) * 256 + threadIdx.x;
    if (e >= E) return;
    int c = col[e];
    int p = min(7, (int)((float)c * pscale));
    if (p != part) return;
    int pos = atomicAdd(&cursor[c], 1);
    eid[pos] = (ushort)row[e];
}

// ---------------- fused fp32 -> bf16 conversion: x then 4 weights ----------------
__global__ __launch_bounds__(256) void gc_cvt_all(const float* __restrict__ x,
                                                  const float* __restrict__ Wa,
                                                  const float* __restrict__ Wb,
                                                  const float* __restrict__ Wc,
                                                  const float* __restrict__ Wd,
                                                  ushort* __restrict__ xb,
                                                  ushort* __restrict__ wb, int n8x) {
    int i = blockIdx.x * 256 + threadIdx.x;
    const float* src;
    ushort* dst;
    int off;
    if (i < n8x) {
        src = x; dst = xb; off = i;
    } else {
        int k = i - n8x;
        if (k >= 8192) return;
        int seg = k >> 11;
        off = k & 2047;
        src = (seg == 0) ? Wa : (seg == 1) ? Wb : (seg == 2) ? Wc : Wd;
        dst = wb + (size_t)seg * 16384;
    }
    const float4* s4 = (const float4*)src;
    float4 a = s4[off * 2], b = s4[off * 2 + 1];
    uint4 o;
    o.x = (uint)f2b(a.x) | ((uint)f2b(a.y) << 16);
    o.y = (uint)f2b(a.z) | ((uint)f2b(a.w) << 16);
    o.z = (uint)f2b(b.x) | ((uint)f2b(b.y) << 16);
    o.w = (uint)f2b(b.z) | ((uint)f2b(b.w) << 16);
    ((uint4*)dst)[off] = o;
}

// ---------------- gather (bf16 in/out, fp32 accumulate), unroll-8 ----------------
// 16 lanes per node, 16B (8 bf16) per lane. Sequential edge order preserved.
__global__ __launch_bounds__(256) void gc_gather_b(const int* __restrict__ offs,
                                                   const ushort* __restrict__ eid,
                                                   const ushort* __restrict__ src,
                                                   const float* __restrict__ dinv,
                                                   const ushort* __restrict__ selfh,
                                                   const float* __restrict__ bias,
                                                   ushort* __restrict__ dst,
                                                   int n, int do_relu) {
    int node = (blockIdx.x * 256 + threadIdx.x) >> 4;
    if (node >= n) return;
    const int c = threadIdx.x & 15;
    const int s = offs[node], e = offs[node + 1];
    const bool un = (dinv != nullptr);
    const float dd = un ? dinv[node] : 1.0f;
    const uint4* __restrict__ src4 = (const uint4*)src;  // 16 uint4 per row

    float acc[8];
#pragma unroll
    for (int k = 0; k < 8; ++k) acc[k] = 0.f;

    int j = s;
    for (; j + 7 < e; j += 8) {
        int r[8];
        float sc[8];
        uint4 u[8];
#pragma unroll
        for (int k = 0; k < 8; ++k) r[k] = eid[j + k];
#pragma unroll
        for (int k = 0; k < 8; ++k) sc[k] = un ? dinv[r[k]] * dd : 1.0f;
#pragma unroll
        for (int k = 0; k < 8; ++k) u[k] = src4[(size_t)r[k] * 16 + c];
#pragma unroll
        for (int k = 0; k < 8; ++k) fma8(acc, u[k], sc[k]);
    }
    for (; j + 3 < e; j += 4) {
        int r[4];
        float sc[4];
        uint4 u[4];
#pragma unroll
        for (int k = 0; k < 4; ++k) r[k] = eid[j + k];
#pragma unroll
        for (int k = 0; k < 4; ++k) sc[k] = un ? dinv[r[k]] * dd : 1.0f;
#pragma unroll
        for (int k = 0; k < 4; ++k) u[k] = src4[(size_t)r[k] * 16 + c];
#pragma unroll
        for (int k = 0; k < 4; ++k) fma8(acc, u[k], sc[k]);
    }
    for (; j < e; ++j) {
        int r0 = eid[j];
        float s0 = un ? dinv[r0] * dd : 1.0f;
        fma8(acc, src4[(size_t)r0 * 16 + c], s0);
    }
    if (selfh) {
        float di2 = dd * dd;
        fma8(acc, ((const uint4*)selfh)[(size_t)node * 16 + c], di2);
#pragma unroll
        for (int k = 0; k < 8; ++k) acc[k] += bias[c * 8 + k];
    }
    if (do_relu) {
#pragma unroll
        for (int k = 0; k < 8; ++k) acc[k] = fmaxf(acc[k], 0.f);
    }
    uint4 o;
    o.x = (uint)f2b(acc[0]) | ((uint)f2b(acc[1]) << 16);
    o.y = (uint)f2b(acc[2]) | ((uint)f2b(acc[3]) << 16);
    o.z = (uint)f2b(acc[4]) | ((uint)f2b(acc[5]) << 16);
    o.w = (uint)f2b(acc[6]) | ((uint)f2b(acc[7]) << 16);
    ((uint4*)dst)[(size_t)node * 16 + c] = o;
}

// ---------------- MFMA GEMM: out = A1@W1.T (+ A2@W2.T) (+bias) (relu), bf16 ----------
__global__ __launch_bounds__(256) void gc_gemm_mfma(const ushort* __restrict__ A1,
                                                    const ushort* __restrict__ W1,
                                                    const ushort* __restrict__ A2,
                                                    const ushort* __restrict__ W2,
                                                    const float* __restrict__ bias,
                                                    ushort* __restrict__ out,
                                                    int nrows, int do_relu) {
    __shared__ ushort lds[128 * 136];  // 34816 B; epilogue reuses first 17408 B
    const int t = threadIdx.x;
    const int w = t >> 6;
    const int l = t & 63;
    const int lr = l & 15;   // A row in tile / B col in tile
    const int g = l >> 4;    // k-group
    const int row0 = blockIdx.x * 64 + w * 16;

    f32x4 acc[8];
#pragma unroll
    for (int i = 0; i < 8; ++i) acc[i] = (f32x4){0.f, 0.f, 0.f, 0.f};

    const int nmat = (A2 != nullptr) ? 2 : 1;
    for (int mat = 0; mat < nmat; ++mat) {
        const ushort* __restrict__ A = mat ? A2 : A1;
        const ushort* __restrict__ W = mat ? W2 : W1;
        __syncthreads();
        // stage W: 128 rows x 16 chunks of 16B = 2048 chunks
#pragma unroll
        for (int i = 0; i < 8; ++i) {
            int cid = i * 256 + t;
            int r = cid >> 4, ch = cid & 15;
            *(uint4*)(&lds[r * 136 + ch * 8]) = ((const uint4*)W)[cid];
        }
        __syncthreads();

        short8 af[4];
        const int arow = row0 + lr;
        const bool ok = arow < nrows;
#pragma unroll
        for (int ks = 0; ks < 4; ++ks) {
            if (ok)
                af[ks] = *(const short8*)(A + (size_t)arow * 128 + ks * 32 + g * 8);
            else
                af[ks] = (short8){0, 0, 0, 0, 0, 0, 0, 0};
        }
#pragma unroll
        for (int ct = 0; ct < 8; ++ct) {
#pragma unroll
            for (int ks = 0; ks < 4; ++ks) {
                short8 bf = *(const short8*)(&lds[(ct * 16 + lr) * 136 + ks * 32 + g * 8]);
                acc[ct] = __builtin_amdgcn_mfma_f32_16x16x32_bf16(af[ks], bf, acc[ct], 0, 0, 0);
            }
        }
    }

    float bv[8];
#pragma unroll
    for (int ct = 0; ct < 8; ++ct) bv[ct] = bias ? bias[ct * 16 + lr] : 0.f;

    __syncthreads();
    ushort* ep = &lds[w * (16 * 136)];
#pragma unroll
    for (int ct = 0; ct < 8; ++ct) {
#pragma unroll
        for (int r = 0; r < 4; ++r) {
            float v = acc[ct][r] + bv[ct];
            if (do_relu) v = fmaxf(v, 0.f);
            ep[(g * 4 + r) * 136 + ct * 16 + lr] = f2b(v);
        }
    }
    __syncthreads();
#pragma unroll
    for (int i = 0; i < 4; ++i) {
        int rr = i * 4 + g;
        int grow = row0 + rr;
        if (grow < nrows) {
            uint4 vv = *(uint4*)(&ep[rr * 136 + lr * 8]);
            ((uint4*)out)[(size_t)grow * 16 + lr] = vv;
        }
    }
}

// ---------------- pooling (bf16 in, fp32 accumulate; batch sorted) ----------------
__global__ __launch_bounds__(256) void gc_pool(const ushort* __restrict__ h,
                                               const int* __restrict__ batch,
                                               float* __restrict__ psum,
                                               float* __restrict__ pcnt, int n) {
    int base = blockIdx.x * 128;
    int sub = threadIdx.x >> 6;
    int fp = threadIdx.x & 63;
    int start = base + sub * 32;
    int end = min(start + 32, n);
    if (start >= end) return;
    int cur = batch[start];
    float s0 = 0.f, s1 = 0.f;
    int run = 0;
    const uint* h2 = (const uint*)h;
    for (int node = start; node < end; ++node) {
        int g = batch[node];
        if (g != cur) {
            unsafeAtomicAdd(&psum[cur * HID + fp * 2 + 0], s0);
            unsafeAtomicAdd(&psum[cur * HID + fp * 2 + 1], s1);
            if (fp == 0) unsafeAtomicAdd(&pcnt[cur], (float)run);
            s0 = s1 = 0.f; run = 0; cur = g;
        }
        uint u = h2[(size_t)node * 64 + fp];
        s0 += __uint_as_float(u << 16);
        s1 += __uint_as_float(u & 0xffff0000u);
        ++run;
    }
    unsafeAtomicAdd(&psum[cur * HID + fp * 2 + 0], s0);
    unsafeAtomicAdd(&psum[cur * HID + fp * 2 + 1], s1);
    if (fp == 0) unsafeAtomicAdd(&pcnt[cur], (float)run);
}

// ---------------- fused finalize: xn row g + out row g (one block per graph) -------
__global__ __launch_bounds__(128) void gc_finalize(const float* __restrict__ psum,
                                                   const float* __restrict__ pcnt,
                                                   const float* __restrict__ Wl,
                                                   const float* __restrict__ bl,
                                                   float* __restrict__ xn,
                                                   float* __restrict__ outp, int C) {
    int g = blockIdx.x;
    int f = threadIdx.x;
    __shared__ float xrow[128];
    __shared__ float s2[2];
    float cn = fmaxf(pcnt[g], 1.0f);
    float v = psum[g * HID + f] / cn;
    float ss = v * v;
#pragma unroll
    for (int off = 32; off >= 1; off >>= 1) ss += __shfl_xor(ss, off, 64);
    if ((f & 63) == 0) s2[f >> 6] = ss;
    __syncthreads();
    float denom = fmaxf(sqrtf(s2[0] + s2[1]), 1e-12f);
    float xv = v / denom;
    xn[g * HID + f] = xv;
    xrow[f] = xv;
    __syncthreads();
    if (f < 64) {
        for (int cc = 0; cc < C; ++cc) {
            float w0 = Wl[cc * HID + 2 * f + 0];
            float w1 = Wl[cc * HID + 2 * f + 1];
            float nrm = w0 * w0 + w1 * w1;
            float dot = xrow[2 * f] * w0 + xrow[2 * f + 1] * w1;
#pragma unroll
            for (int off = 32; off >= 1; off >>= 1) {
                nrm += __shfl_xor(nrm, off, 64);
                dot += __shfl_xor(dot, off, 64);
            }
            if (f == 0) outp[g * C + cc] = dot / fmaxf(sqrtf(nrm), 1e-12f) + bl[cc];
        }
    }
}

extern "C" void kernel_launch(void* const* d_in, const int* in_sizes, int n_in,
                              void* d_out, int out_size, void* d_ws, size_t ws_size,
                              hipStream_t stream) {
    const float* x      = (const float*)d_in[0];
    const int*   ei     = (const int*)d_in[1];
    const int*   batch  = (const int*)d_in[2];
    const float* W1_rel = (const float*)d_in[3];
    const float* b1     = (const float*)d_in[4];
    const float* W1_root= (const float*)d_in[5];
    const float* W2     = (const float*)d_in[6];
    const float* b2     = (const float*)d_in[7];
    const float* W3     = (const float*)d_in[8];
    const float* b3     = (const float*)d_in[9];
    const float* Wl     = (const float*)d_in[10];
    const float* bl     = (const float*)d_in[11];

    const int N = in_sizes[0] / HID;     // 50000
    const int E = in_sizes[1] / 2;       // 800000
    const int C = 10;
    const int G = out_size / (HID + C);  // 128

    const int* row = ei;
    const int* col = ei + E;

    // workspace layout (16B alignment maintained; psum..degi contiguous zero region)
    ushort* xb  = (ushort*)d_ws;                      // N*128 bf16
    ushort* hb0 = xb  + (size_t)N * HID;              // N*128 bf16
    ushort* hb1 = hb0 + (size_t)N * HID;              // N*128 bf16
    ushort* wb  = hb1 + (size_t)N * HID;              // 4*16384 bf16 weights
    float* dinv = (float*)(wb + 4 * 16384);           // N
    float* psum = dinv + N;                           // G*128  --+ zeroed
    float* pcnt = psum + (size_t)G * HID;             // G        | together
    int*   degi = (int*)(pcnt + G);                   // N      --+
    int*   offs = degi + N;                           // N+1
    int*   curs = offs + N + 1;                       // N
    ushort* eid = (ushort*)(curs + N);                // E (ushort; N<65536)
    int*   bsum = (int*)(eid + ((E + 1) & ~1));       // ceil(N/256)

    float* xn   = (float*)d_out;
    float* outp = xn + (size_t)G * HID;

    const int eb256 = (E + 255) / 256;
    const int nb256 = (N + 255) / 256;        // scan block count (<=256 required)
    const int gthb  = (N * 16 + 255) / 256;   // gather: 16 lanes/node
    const int gmb   = (N + 63) / 64;          // gemm: 64 rows/block
    const float pscale = 8.0f / (float)N;     // node -> partition in [0,8)
    const int n8x   = N * HID / 8;            // x cvt chunks
    const int cvb   = (n8x + 8192 + 255) / 256;

    // ---- zero psum+pcnt+degi in one memset ----
    hipMemsetAsync(psum, 0, ((size_t)G * HID + G + N) * sizeof(float), stream);

    // ---- CSR build + dinv ----
    gc_deg_count<<<eb256, 256, 0, stream>>>(col, degi, E);
    gc_scan_part<<<nb256, 256, 0, stream>>>(degi, bsum, N);
    gc_scan_top<<<1, 256, 0, stream>>>(bsum, nb256);
    gc_scan_final<<<nb256, 256, 0, stream>>>(degi, bsum, offs, curs, dinv, N);
    gc_fill_xcd<<<eb256 * 8, 256, 0, stream>>>(row, col, curs, eid, E, pscale);

    // ---- conversions (x + all 4 weights, one launch) ----
    gc_cvt_all<<<cvb, 256, 0, stream>>>(x, W1_rel, W1_root, W2, W3, xb, wb, n8x);

    // conv1: agg = gather(x); h1 = relu(agg@W1_rel.T + x@W1_root.T + b1)
    gc_gather_b<<<gthb, 256, 0, stream>>>(offs, eid, xb, nullptr, nullptr, nullptr, hb0, N, 0);
    gc_gemm_mfma<<<gmb, 256, 0, stream>>>(hb0, wb, xb, wb + 16384, b1, hb1, N, 1);

    // conv2: hp2 = h1@W2.T; h2 = relu(gatherN(hp2) + hp2*dinv^2 + b2)
    gc_gemm_mfma<<<gmb, 256, 0, stream>>>(hb1, wb + 2 * 16384, nullptr, nullptr, nullptr, hb0, N, 0);
    gc_gather_b<<<gthb, 256, 0, stream>>>(offs, eid, hb0, dinv, hb0, b2, hb1, N, 1);

    // conv3: hp3 = h2@W3.T; h3 = gatherN(hp3) + hp3*dinv^2 + b3
    gc_gemm_mfma<<<gmb, 256, 0, stream>>>(hb1, wb + 3 * 16384, nullptr, nullptr, nullptr, hb0, N, 0);
    gc_gather_b<<<gthb, 256, 0, stream>>>(offs, eid, hb0, dinv, hb0, b3, hb1, N, 0);

    // pool + fused head
    gc_pool<<<(N + 127) / 128, 256, 0, stream>>>(hb1, batch, psum, pcnt, N);
    gc_finalize<<<G, 128, 0, stream>>>(psum, pcnt, Wl, bl, xn, outp, C);
}